// Round 1
// baseline (395.361 us; speedup 1.0000x reference)
//
#include <hip/hip_runtime.h>
#include <math.h>
#include <stdint.h>

#define FLA_EPS 1e-5f

constexpr int kB  = 16;
constexpr int kD  = 256;   // d == C == 256
constexpr int kN  = 4096;  // H*W
constexpr int kO3 = 768;   // 3*d

typedef __attribute__((ext_vector_type(8))) short bf16x8;
typedef __attribute__((ext_vector_type(4))) float f32x4;

__device__ __forceinline__ unsigned short f2bf(float f) {
  union { float f; uint32_t u; } v; v.f = f;
  uint32_t r = v.u + 0x7FFFu + ((v.u >> 16) & 1u);  // RNE
  return (unsigned short)(r >> 16);
}
__device__ __forceinline__ float bf2f(unsigned short h) {
  union { uint32_t u; float f; } v; v.u = ((uint32_t)h) << 16; return v.f;
}
__device__ __forceinline__ void gl_lds16(const void* g, void* l) {
  __builtin_amdgcn_global_load_lds(
      (const __attribute__((address_space(1))) uint32_t*)g,
      (__attribute__((address_space(3))) uint32_t*)l, 16, 0, 0);
}

// ---------------------------------------------------------------------------
// fp32 -> bf16 weight convert
// ---------------------------------------------------------------------------
__global__ __launch_bounds__(256) void convert_w(
    const float* __restrict__ w, unsigned short* __restrict__ wb, int n) {
  const int i = blockIdx.x * 256 + threadIdx.x;
  if (i < n) wb[i] = f2bf(w[i]);
}

// ---------------------------------------------------------------------------
// x [B][C][N] fp32 -> xt [B][N][C] bf16. 64x64 tiles, float4 loads,
// ushort4 packed stores.
// ---------------------------------------------------------------------------
__global__ __launch_bounds__(256) void transpose_x2(
    const float* __restrict__ x, unsigned short* __restrict__ xt) {
  __shared__ float t[64][65];
  const int tid = threadIdx.x;
  const int n0 = blockIdx.x * 64, c0 = blockIdx.y * 64, b = blockIdx.z;
  const float* xb = x + ((long)b * kD + c0) * kN + n0;
#pragma unroll
  for (int r = 0; r < 4; ++r) {
    const int idx = tid + r * 256;  // 1024 float4 total
    const int c = idx >> 4, n4 = (idx & 15) * 4;
    const float4 v = *(const float4*)(xb + (long)c * kN + n4);
    t[c][n4] = v.x; t[c][n4 + 1] = v.y; t[c][n4 + 2] = v.z; t[c][n4 + 3] = v.w;
  }
  __syncthreads();
  unsigned short* xtb = xt + ((long)b * kN + n0) * kD + c0;
#pragma unroll
  for (int r = 0; r < 4; ++r) {
    const int idx = tid + r * 256;
    const int n = idx >> 4, cg = (idx & 15) * 4;
    ushort4 o;
    o.x = f2bf(t[cg + 0][n]); o.y = f2bf(t[cg + 1][n]);
    o.z = f2bf(t[cg + 2][n]); o.w = f2bf(t[cg + 3][n]);
    *(ushort4*)&xtb[(long)n * kD + cg] = o;
  }
}

// ---------------------------------------------------------------------------
// Fused qkv GEMM + feature map, weight-stationary.
// Block: one of q/k/v (256 out ch) x 256 pixels (4 n-tiles of 64).
//   - W fragments live in 128 VGPRs (aw[8][4]), loaded once per block.
//   - x-tile staged full-K (64px x 256k = 32KB) per n-tile, double-buffered,
//     XOR-swizzled (pre-swizzled gl_lds source + swizzled ds_read).
//   - ONE barrier per n-tile (colbuf double-buffered).
// type 0 (q): feature-map, write qt[n][c] bf16 (transposed)
// type 1 (k): feature-map, write kb[c][n] bf16, fused kmean atomicAdd
// type 2 (v): bias only,  write vb[c][n] bf16
// ---------------------------------------------------------------------------
__global__ __launch_bounds__(256, 2) void qkv4_mfma(
    const unsigned short* __restrict__ Wb, const unsigned short* __restrict__ xt,
    const float* __restrict__ bias, unsigned short* __restrict__ qt,
    unsigned short* __restrict__ kb, unsigned short* __restrict__ vb,
    float* __restrict__ km) {
  __shared__ unsigned short sB[2][64 * 256] __attribute__((aligned(16)));
  __shared__ float sBias[256];
  __shared__ float colbuf[2][4][64];
  const int tid = threadIdx.x;
  const int g = blockIdx.x;                 // n-group: 4 tiles of 64 px
  const int type = blockIdx.y, b = blockIdx.z;
  const int m0 = type * 256;
  const unsigned short* xtb = xt + (long)b * kN * kD;
  const int lane = tid & 63, w = tid >> 6;
  const int lr = lane & 15, lq = lane >> 4;
  sBias[tid] = bias[m0 + tid];

  // ---- W fragments -> registers (weight-stationary) ----
  bf16x8 aw[8][4];
  {
    const unsigned short* wp = Wb + (long)(m0 + w * 64 + lr) * kD + lq * 8;
#pragma unroll
    for (int kk = 0; kk < 8; ++kk)
#pragma unroll
      for (int mt = 0; mt < 4; ++mt)
        aw[kk][mt] = *(const bf16x8*)(wp + (long)(mt * 16) * kD + kk * 32);
  }

  // ---- stage tile 0 (swizzled source, linear LDS dest) ----
  {
    const int nb = g * 256;
#pragma unroll
    for (int r = 0; r < 8; ++r) {
      const int c = tid + r * 256;          // 0..2047 chunks of 16B
      const int n = c >> 5;
      const int slot = (c & 31) ^ (n & 7);  // inverse swizzle on source
      gl_lds16(xtb + (long)(nb + n) * kD + slot * 8, &sB[0][c * 8]);
    }
  }
  __syncthreads();

  for (int t = 0; t < 4; ++t) {
    const int n0 = g * 256 + t * 64;
    const int cur = t & 1;
    // prefetch next tile into other buffer (loads stay in flight over MFMA)
    if (t < 3) {
#pragma unroll
      for (int r = 0; r < 8; ++r) {
        const int c = tid + r * 256;
        const int n = c >> 5;
        const int slot = (c & 31) ^ (n & 7);
        gl_lds16(xtb + (long)(n0 + 64 + n) * kD + slot * 8, &sB[cur ^ 1][c * 8]);
      }
    }

    f32x4 acc[4][4];
#pragma unroll
    for (int i = 0; i < 4; ++i)
#pragma unroll
      for (int j = 0; j < 4; ++j) acc[i][j] = (f32x4){0.f, 0.f, 0.f, 0.f};

    // 128 MFMAs, zero barriers inside
#pragma unroll
    for (int kk = 0; kk < 8; ++kk) {
      bf16x8 bfr[4];
#pragma unroll
      for (int nt = 0; nt < 4; ++nt) {
        const int row = nt * 16 + lr;
        const int e = (row * 256 + kk * 32 + lq * 8) ^ ((lr & 7) << 3);
        bfr[nt] = *(const bf16x8*)&sB[cur][e];
      }
#pragma unroll
      for (int mt = 0; mt < 4; ++mt)
#pragma unroll
        for (int nt = 0; nt < 4; ++nt)
          acc[mt][nt] = __builtin_amdgcn_mfma_f32_16x16x32_bf16(
              aw[kk][mt], bfr[nt], acc[mt][nt], 0, 0, 0);
    }

    if (type < 2) {
      float part[4] = {0.f, 0.f, 0.f, 0.f};
#pragma unroll
      for (int mt = 0; mt < 4; ++mt) {
#pragma unroll
        for (int rr = 0; rr < 4; ++rr) {
          const float bv = sBias[w * 64 + mt * 16 + lq * 4 + rr];
#pragma unroll
          for (int nt = 0; nt < 4; ++nt) {
            const float r_ = fmaxf(acc[mt][nt][rr] + bv, 0.f) + FLA_EPS;
            const float tt = r_ * r_;
            acc[mt][nt][rr] = tt;
            part[nt] += tt * tt;
          }
        }
      }
#pragma unroll
      for (int nt = 0; nt < 4; ++nt) {
        part[nt] += __shfl_xor(part[nt], 16);
        part[nt] += __shfl_xor(part[nt], 32);
      }
      if (lq == 0)
#pragma unroll
        for (int nt = 0; nt < 4; ++nt) colbuf[cur][w][nt * 16 + lr] = part[nt];
    }
    // single barrier per tile: colbuf visibility + prefetch drain + sB reuse
    __syncthreads();

    if (type < 2) {
      float inv[4];
#pragma unroll
      for (int nt = 0; nt < 4; ++nt) {
        const int col = nt * 16 + lr;
        const float S = colbuf[cur][0][col] + colbuf[cur][1][col] +
                        colbuf[cur][2][col] + colbuf[cur][3][col];
        inv[nt] = 1.f / fmaxf(sqrtf(S), 1e-12f);
      }
      if (type == 0) {  // qt[n][c]
        unsigned short* qtb = qt + (long)b * kN * kD;
#pragma unroll
        for (int mt = 0; mt < 4; ++mt)
#pragma unroll
          for (int nt = 0; nt < 4; ++nt) {
            ushort4 o;
            o.x = f2bf(acc[mt][nt][0] * inv[nt]);
            o.y = f2bf(acc[mt][nt][1] * inv[nt]);
            o.z = f2bf(acc[mt][nt][2] * inv[nt]);
            o.w = f2bf(acc[mt][nt][3] * inv[nt]);
            *(ushort4*)&qtb[(long)(n0 + nt * 16 + lr) * kD +
                            w * 64 + mt * 16 + lq * 4] = o;
          }
      } else {  // kb[c][n] + fused kmean
        unsigned short* kbb = kb + (long)b * kD * kN;
#pragma unroll
        for (int mt = 0; mt < 4; ++mt)
#pragma unroll
          for (int rr = 0; rr < 4; ++rr) {
            const int ch = w * 64 + mt * 16 + lq * 4 + rr;
            float ks = 0.f;
#pragma unroll
            for (int nt = 0; nt < 4; ++nt) {
              const unsigned short sv = f2bf(acc[mt][nt][rr] * inv[nt]);
              kbb[(long)ch * kN + n0 + nt * 16 + lr] = sv;
              ks += bf2f(sv);
            }
            ks += __shfl_xor(ks, 1);
            ks += __shfl_xor(ks, 2);
            ks += __shfl_xor(ks, 4);
            ks += __shfl_xor(ks, 8);
            if (lr == 0) atomicAdd(&km[b * kD + ch], ks * (1.f / kN));
          }
      }
    } else {  // v: bias only -> vb[c][n]
      unsigned short* vbb = vb + (long)b * kD * kN;
#pragma unroll
      for (int mt = 0; mt < 4; ++mt)
#pragma unroll
        for (int rr = 0; rr < 4; ++rr) {
          const int ch = w * 64 + mt * 16 + lq * 4 + rr;
          const float bv = sBias[ch];
#pragma unroll
          for (int nt = 0; nt < 4; ++nt)
            vbb[(long)ch * kN + n0 + nt * 16 + lr] = f2bf(acc[mt][nt][rr] + bv);
        }
    }
  }
}

// ---------------------------------------------------------------------------
// Tpart[s][b][i][j] = sum_{n in slice s} vb[i][n] * kb[j][n]  (MFMA, 8-way K)
// ---------------------------------------------------------------------------
__global__ __launch_bounds__(256) void vkt2_mfma(
    const unsigned short* __restrict__ vb, const unsigned short* __restrict__ kb,
    float* __restrict__ Tpart) {
  __shared__ unsigned short sA[128 * 32] __attribute__((aligned(16)));
  __shared__ unsigned short sB[128 * 32] __attribute__((aligned(16)));
  const int tid = threadIdx.x;
  const int i0 = blockIdx.x * 128, j0 = blockIdx.y * 128;
  const int b = blockIdx.z >> 3, s = blockIdx.z & 7;
  const unsigned short* vbb = vb + (long)b * kD * kN;
  const unsigned short* kbb = kb + (long)b * kD * kN;
  const int lane = tid & 63, w = tid >> 6;
  const int wm = (w & 1) * 64, wn = (w >> 1) * 64;
  const int lr = lane & 15, lq = lane >> 4;
  const int c0 = tid, c1 = 256 + tid;
  const int am0 = c0 >> 2, ak0 = (c0 & 3) * 8;
  const int am1 = c1 >> 2, ak1 = (c1 & 3) * 8;

  f32x4 acc[4][4];
#pragma unroll
  for (int i = 0; i < 4; ++i)
#pragma unroll
    for (int j = 0; j < 4; ++j) acc[i][j] = (f32x4){0.f, 0.f, 0.f, 0.f};

  for (int n0 = s * 512; n0 < s * 512 + 512; n0 += 32) {
    gl_lds16(vbb + (long)(i0 + am0) * kN + n0 + ak0, &sA[c0 * 8]);
    gl_lds16(vbb + (long)(i0 + am1) * kN + n0 + ak1, &sA[c1 * 8]);
    gl_lds16(kbb + (long)(j0 + am0) * kN + n0 + ak0, &sB[c0 * 8]);
    gl_lds16(kbb + (long)(j0 + am1) * kN + n0 + ak1, &sB[c1 * 8]);
    __syncthreads();
    bf16x8 af[4], bf[4];
#pragma unroll
    for (int mt = 0; mt < 4; ++mt)
      af[mt] = *(const bf16x8*)&sA[(wm + mt * 16 + lr) * 32 + lq * 8];
#pragma unroll
    for (int nt = 0; nt < 4; ++nt)
      bf[nt] = *(const bf16x8*)&sB[(wn + nt * 16 + lr) * 32 + lq * 8];
#pragma unroll
    for (int mt = 0; mt < 4; ++mt)
#pragma unroll
      for (int nt = 0; nt < 4; ++nt)
        acc[mt][nt] = __builtin_amdgcn_mfma_f32_16x16x32_bf16(
            af[mt], bf[nt], acc[mt][nt], 0, 0, 0);
    __syncthreads();
  }
  float* Tp = Tpart + ((long)s * kB + b) * kD * kD;
#pragma unroll
  for (int mt = 0; mt < 4; ++mt)
#pragma unroll
    for (int nt = 0; nt < 4; ++nt) {
      const int j = j0 + wn + nt * 16 + lr;
#pragma unroll
      for (int r = 0; r < 4; ++r) {
        const int i = i0 + wm + mt * 16 + lq * 4 + r;
        Tp[(long)i * kD + j] = acc[mt][nt][r];
      }
    }
}

// ---------------------------------------------------------------------------
// Tt[b][i][j] bf16 = (1/N) * sum_s Tpart[s][b][i][j]
// ---------------------------------------------------------------------------
__global__ __launch_bounds__(256) void tconvert(
    const float* __restrict__ Tpart, unsigned short* __restrict__ Tt) {
  const long idx = (long)blockIdx.x * 256 + threadIdx.x;
  float s = 0.f;
#pragma unroll
  for (int p = 0; p < 8; ++p) s += Tpart[(long)p * 1048576 + idx];
  Tt[idx] = f2bf(s * (1.f / 4096.f));
}

// ---------------------------------------------------------------------------
// Depthwise 5x5 conv: vb bf16 -> dwp bf16 (incl. bias).
// ---------------------------------------------------------------------------
__global__ __launch_bounds__(256) void dwconv3(
    const unsigned short* __restrict__ vb, const float* __restrict__ dwc_w,
    const float* __restrict__ dwc_b, unsigned short* __restrict__ dwp) {
  __shared__ float tile[68][80];
  __shared__ float wt[32];
  const int c = blockIdx.x, b = blockIdx.y;
  const int tid = threadIdx.x;
  if (tid < 25) wt[tid] = dwc_w[c * 25 + tid];
  {  // zero the whole tile (simple halo init): 68*80/4 = 1360 float4
    const float4 z4 = {0.f, 0.f, 0.f, 0.f};
    float* tf = &tile[0][0];
#pragma unroll
    for (int r = 0; r < 6; ++r) {
      const int i = tid + r * 256;
      if (i < 1360) *(float4*)(tf + i * 4) = z4;
    }
  }
  __syncthreads();
  const unsigned short* vp = vb + ((long)b * kD + c) * kN;
#pragma unroll
  for (int r = 0; r < 2; ++r) {  // 512 uint4 chunks (8 bf16 each)
    const int ch = tid + r * 256;
    const int row = ch >> 3, sub = ch & 7;
    const uint4 u = *(const uint4*)(vp + row * 64 + sub * 8);
    const unsigned short* p = (const unsigned short*)&u;
    float4 f0, f1;
    f0.x = bf2f(p[0]); f0.y = bf2f(p[1]); f0.z = bf2f(p[2]); f0.w = bf2f(p[3]);
    f1.x = bf2f(p[4]); f1.y = bf2f(p[5]); f1.z = bf2f(p[6]); f1.w = bf2f(p[7]);
    *(float4*)&tile[row + 2][4 + sub * 8] = f0;
    *(float4*)&tile[row + 2][8 + sub * 8] = f1;
  }
  __syncthreads();
  float w_[25];
#pragma unroll
  for (int i = 0; i < 25; ++i) w_[i] = wt[i];
  const float bias = dwc_b[c];
  const int pr = tid >> 4, pc = tid & 15;
  const int oy0 = pr * 4, ox0 = pc * 4;
  float win[8][12];
#pragma unroll
  for (int r = 0; r < 8; ++r) {
    *(float4*)&win[r][0] = *(const float4*)&tile[oy0 + r][ox0 + 0];
    *(float4*)&win[r][4] = *(const float4*)&tile[oy0 + r][ox0 + 4];
    *(float4*)&win[r][8] = *(const float4*)&tile[oy0 + r][ox0 + 8];
  }
  unsigned short* yp = dwp + ((long)b * kD + c) * kN;
#pragma unroll
  for (int dy = 0; dy < 4; ++dy) {
    ushort4 o;
    unsigned short* op = (unsigned short*)&o;
#pragma unroll
    for (int dx = 0; dx < 4; ++dx) {
      float s = bias;
#pragma unroll
      for (int ky = 0; ky < 5; ++ky)
#pragma unroll
        for (int kx = 0; kx < 5; ++kx)
          s += win[dy + ky][dx + kx + 2] * w_[ky * 5 + kx];
      op[dx] = f2bf(s);
    }
    *(ushort4*)&yp[(oy0 + dy) * 64 + ox0] = o;
  }
}

// ---------------------------------------------------------------------------
// attn: D[pix][ch] = sum_j qt[n][j] Tt[ch][j]; fused z (kmean.q), /z,
// RMSNorm over ch, *norm_w, + dw  -> yt[n][ch] bf16.
// ---------------------------------------------------------------------------
__global__ __launch_bounds__(256) void attn2_mfma(
    const unsigned short* __restrict__ qt, const unsigned short* __restrict__ Tt,
    const float* __restrict__ kmean, const float* __restrict__ norm_w,
    const unsigned short* __restrict__ dwp, unsigned short* __restrict__ yt) {
  __shared__ unsigned char smem[36864] __attribute__((aligned(16)));
  __shared__ float sKm[256];
  __shared__ float sNw[256];
  __shared__ float zbuf[64];
  __shared__ float rbuf[4][64];
  unsigned short* sQ = (unsigned short*)smem;            // 64 x 32
  unsigned short* sT = (unsigned short*)(smem + 4096);   // 256 x 32
  unsigned short* sDw = (unsigned short*)smem;           // 256 x 72 (reuse)
  const int tid = threadIdx.x;
  const int n0 = blockIdx.x * 64, b = blockIdx.y;
  const unsigned short* qtb = qt + (long)b * kN * kD;
  const unsigned short* Ttb = Tt + (long)b * kD * kD;
  sKm[tid] = kmean[b * kD + tid];
  sNw[tid] = norm_w[tid];
  const int lane = tid & 63, w = tid >> 6;
  const int lr = lane & 15, lq = lane >> 4;

  f32x4 acc[4][4];
#pragma unroll
  for (int i = 0; i < 4; ++i)
#pragma unroll
    for (int j = 0; j < 4; ++j) acc[i][j] = (f32x4){0.f, 0.f, 0.f, 0.f};
  float zp[4] = {0.f, 0.f, 0.f, 0.f};

  for (int k0 = 0; k0 < 256; k0 += 32) {
    {
      const int c = tid;
      gl_lds16(qtb + (long)(n0 + (c >> 2)) * kD + k0 + (c & 3) * 8, &sQ[c * 8]);
    }
#pragma unroll
    for (int r = 0; r < 4; ++r) {
      const int c = tid + r * 256;
      gl_lds16(Ttb + (long)(c >> 2) * kD + k0 + (c & 3) * 8, &sT[c * 8]);
    }
    __syncthreads();
    bf16x8 af[4], bf[4];
#pragma unroll
    for (int mt = 0; mt < 4; ++mt)
      af[mt] = *(const bf16x8*)&sQ[(mt * 16 + lr) * 32 + lq * 8];
#pragma unroll
    for (int nt = 0; nt < 4; ++nt)
      bf[nt] = *(const bf16x8*)&sT[(w * 64 + nt * 16 + lr) * 32 + lq * 8];
#pragma unroll
    for (int mt = 0; mt < 4; ++mt)
#pragma unroll
      for (int j = 0; j < 8; ++j)
        zp[mt] += bf2f((unsigned short)af[mt][j]) * sKm[k0 + lq * 8 + j];
#pragma unroll
    for (int mt = 0; mt < 4; ++mt)
#pragma unroll
      for (int nt = 0; nt < 4; ++nt)
        acc[mt][nt] = __builtin_amdgcn_mfma_f32_16x16x32_bf16(
            af[mt], bf[nt], acc[mt][nt], 0, 0, 0);
    __syncthreads();
  }

  const unsigned short* dwpb = dwp + (long)b * kD * kN;
#pragma unroll
  for (int it = 0; it < 8; ++it) {
    const int c = tid + it * 256;
    const int row = c >> 3, sub = c & 7;
    uint4 t4 = *(const uint4*)(dwpb + (long)row * kN + n0 + sub * 8);
    *(uint4*)&sDw[row * 72 + sub * 8] = t4;
  }
#pragma unroll
  for (int mt = 0; mt < 4; ++mt) {
    zp[mt] += __shfl_xor(zp[mt], 16);
    zp[mt] += __shfl_xor(zp[mt], 32);
  }
  if (w == 0 && lq == 0)
#pragma unroll
    for (int mt = 0; mt < 4; ++mt) zbuf[mt * 16 + lr] = zp[mt];
  __syncthreads();

  float ss[4][4];
#pragma unroll
  for (int mt = 0; mt < 4; ++mt)
#pragma unroll
    for (int r = 0; r < 4; ++r) {
      const float invz = 1.f / (zbuf[mt * 16 + lq * 4 + r] + FLA_EPS);
      float s = 0.f;
#pragma unroll
      for (int nt = 0; nt < 4; ++nt) {
        acc[mt][nt][r] *= invz;
        s += acc[mt][nt][r] * acc[mt][nt][r];
      }
      ss[mt][r] = s;
    }
#pragma unroll
  for (int mt = 0; mt < 4; ++mt)
#pragma unroll
    for (int r = 0; r < 4; ++r) {
      ss[mt][r] += __shfl_xor(ss[mt][r], 1);
      ss[mt][r] += __shfl_xor(ss[mt][r], 2);
      ss[mt][r] += __shfl_xor(ss[mt][r], 4);
      ss[mt][r] += __shfl_xor(ss[mt][r], 8);
    }
  if (lr == 0)
#pragma unroll
    for (int mt = 0; mt < 4; ++mt)
#pragma unroll
      for (int r = 0; r < 4; ++r) rbuf[w][mt * 16 + lq * 4 + r] = ss[mt][r];
  __syncthreads();

  unsigned short* ytb = yt + (long)b * kN * kD;
  float nw[4];
#pragma unroll
  for (int nt = 0; nt < 4; ++nt) nw[nt] = sNw[w * 64 + nt * 16 + lr];
#pragma unroll
  for (int mt = 0; mt < 4; ++mt)
#pragma unroll
    for (int r = 0; r < 4; ++r) {
      const int p = mt * 16 + lq * 4 + r;
      const float S = rbuf[0][p] + rbuf[1][p] + rbuf[2][p] + rbuf[3][p];
      const float scl = rsqrtf(S * (1.f / 256.f) + FLA_EPS);
#pragma unroll
      for (int nt = 0; nt < 4; ++nt) {
        const int ch = w * 64 + nt * 16 + lr;
        const float dw = bf2f(sDw[ch * 72 + p]);
        const float o = acc[mt][nt][r] * scl * nw[nt] + dw;
        ytb[(long)(n0 + p) * kD + ch] = f2bf(o);
      }
    }
}

// ---------------------------------------------------------------------------
// proj: out[b][c][n] = proj_w @ yt^T + proj_b  (MFMA, fp32 out)
// ---------------------------------------------------------------------------
__global__ __launch_bounds__(256) void proj2_mfma(
    const unsigned short* __restrict__ Wb, const unsigned short* __restrict__ yt,
    const float* __restrict__ bias, float* __restrict__ out) {
  __shared__ unsigned short sA[128 * 32] __attribute__((aligned(16)));
  __shared__ unsigned short sB[128 * 32] __attribute__((aligned(16)));
  const int tid = threadIdx.x;
  const int n0 = blockIdx.x * 128, m0 = blockIdx.y * 128, b = blockIdx.z;
  const unsigned short* ytb = yt + (long)b * kN * kD;
  const int lane = tid & 63, w = tid >> 6;
  const int wm = (w & 1) * 64, wn = (w >> 1) * 64;
  const int lr = lane & 15, lq = lane >> 4;
  const int c0 = tid, c1 = 256 + tid;
  const int am0 = c0 >> 2, ak0 = (c0 & 3) * 8;
  const int am1 = c1 >> 2, ak1 = (c1 & 3) * 8;

  f32x4 acc[4][4];
#pragma unroll
  for (int i = 0; i < 4; ++i)
#pragma unroll
    for (int j = 0; j < 4; ++j) acc[i][j] = (f32x4){0.f, 0.f, 0.f, 0.f};

  for (int k0 = 0; k0 < 256; k0 += 32) {
    gl_lds16(Wb + (long)(m0 + am0) * kD + k0 + ak0, &sA[c0 * 8]);
    gl_lds16(Wb + (long)(m0 + am1) * kD + k0 + ak1, &sA[c1 * 8]);
    gl_lds16(ytb + (long)(n0 + am0) * kD + k0 + ak0, &sB[c0 * 8]);
    gl_lds16(ytb + (long)(n0 + am1) * kD + k0 + ak1, &sB[c1 * 8]);
    __syncthreads();
    bf16x8 af[4], bf[4];
#pragma unroll
    for (int mt = 0; mt < 4; ++mt)
      af[mt] = *(const bf16x8*)&sA[(wm + mt * 16 + lr) * 32 + lq * 8];
#pragma unroll
    for (int nt = 0; nt < 4; ++nt)
      bf[nt] = *(const bf16x8*)&sB[(wn + nt * 16 + lr) * 32 + lq * 8];
#pragma unroll
    for (int mt = 0; mt < 4; ++mt)
#pragma unroll
      for (int nt = 0; nt < 4; ++nt)
        acc[mt][nt] = __builtin_amdgcn_mfma_f32_16x16x32_bf16(
            af[mt], bf[nt], acc[mt][nt], 0, 0, 0);
    __syncthreads();
  }
  float* ob = out + (long)b * kD * kN;
#pragma unroll
  for (int mt = 0; mt < 4; ++mt)
#pragma unroll
    for (int nt = 0; nt < 4; ++nt) {
      const int n = n0 + wn + nt * 16 + lr;
#pragma unroll
      for (int r = 0; r < 4; ++r) {
        const int m = m0 + wm + mt * 16 + lq * 4 + r;
        ob[(long)m * kN + n] = acc[mt][nt][r] + bias[m];
      }
    }
}

// ---------------------------------------------------------------------------
extern "C" void kernel_launch(void* const* d_in, const int* in_sizes, int n_in,
                              void* d_out, int out_size, void* d_ws,
                              size_t ws_size, hipStream_t stream) {
  const float* x      = (const float*)d_in[0];
  const float* qkv_w  = (const float*)d_in[1];
  const float* qkv_b  = (const float*)d_in[2];
  const float* dwc_w  = (const float*)d_in[3];
  const float* dwc_b  = (const float*)d_in[4];
  const float* norm_w = (const float*)d_in[5];
  const float* proj_w = (const float*)d_in[6];
  const float* proj_b = (const float*)d_in[7];
  float* out = (float*)d_out;
  char* ws = (char*)d_ws;

  constexpr long SZ = 33554432;  // 16*4096*256 * 2B
  unsigned short* qt  = (unsigned short*)(ws);
  unsigned short* kb  = (unsigned short*)(ws + SZ);
  unsigned short* vb  = (unsigned short*)(ws + 2 * SZ);
  unsigned short* dwp = (unsigned short*)(ws + 3 * SZ);
  unsigned short* yt  = (unsigned short*)(ws + 4 * SZ);
  unsigned short* xt  = (unsigned short*)(ws + 5 * SZ);
  float* Tpart        = (float*)(ws + 5 * SZ);        // aliases xt (dead)
  unsigned short* Tt  = (unsigned short*)(ws + 6 * SZ);
  unsigned short* wqb = (unsigned short*)(ws + 6 * SZ + 2097152);
  unsigned short* wpb = (unsigned short*)(ws + 6 * SZ + 2097152 + 393216);
  float* km           = (float*)(ws + 6 * SZ + 2097152 + 393216 + 131072);

  convert_w<<<768, 256, 0, stream>>>(qkv_w, wqb, kO3 * kD);
  convert_w<<<256, 256, 0, stream>>>(proj_w, wpb, kD * kD);
  transpose_x2<<<dim3(64, 4, 16), 256, 0, stream>>>(x, xt);
  hipMemsetAsync(km, 0, kB * kD * sizeof(float), stream);  // fused kmean accum
  qkv4_mfma<<<dim3(16, 3, 16), 256, 0, stream>>>(wqb, xt, qkv_b, qt, kb, vb, km);
  vkt2_mfma<<<dim3(2, 2, 128), 256, 0, stream>>>(vb, kb, Tpart);
  tconvert<<<4096, 256, 0, stream>>>(Tpart, Tt);
  dwconv3<<<dim3(256, 16), 256, 0, stream>>>(vb, dwc_w, dwc_b, dwp);
  attn2_mfma<<<dim3(64, 16), 256, 0, stream>>>(qt, Tt, km, norm_w, dwp, yt);
  proj2_mfma<<<dim3(32, 2, 16), 256, 0, stream>>>(wpb, yt, proj_b, out);
}

// Round 2
// 359.168 us; speedup vs baseline: 1.1008x; 1.1008x over previous
//
#include <hip/hip_runtime.h>
#include <math.h>
#include <stdint.h>

#define FLA_EPS 1e-5f

constexpr int kB  = 16;
constexpr int kD  = 256;   // d == C == 256
constexpr int kN  = 4096;  // H*W
constexpr int kO3 = 768;   // 3*d

typedef __attribute__((ext_vector_type(8))) short bf16x8;
typedef __attribute__((ext_vector_type(4))) float f32x4;

__device__ __forceinline__ unsigned short f2bf(float f) {
  union { float f; uint32_t u; } v; v.f = f;
  uint32_t r = v.u + 0x7FFFu + ((v.u >> 16) & 1u);  // RNE
  return (unsigned short)(r >> 16);
}
__device__ __forceinline__ float bf2f(unsigned short h) {
  union { uint32_t u; float f; } v; v.u = ((uint32_t)h) << 16; return v.f;
}
__device__ __forceinline__ void gl_lds16(const void* g, void* l) {
  __builtin_amdgcn_global_load_lds(
      (const __attribute__((address_space(1))) uint32_t*)g,
      (__attribute__((address_space(3))) uint32_t*)l, 16, 0, 0);
}

// ---------------------------------------------------------------------------
// fp32 -> bf16 weight convert
// ---------------------------------------------------------------------------
__global__ __launch_bounds__(256) void convert_w(
    const float* __restrict__ w, unsigned short* __restrict__ wb, int n) {
  const int i = blockIdx.x * 256 + threadIdx.x;
  if (i < n) wb[i] = f2bf(w[i]);
}

// ---------------------------------------------------------------------------
// x [B][C][N] fp32 -> xt [B][N][C] bf16. 64x64 tiles, float4 loads,
// ushort4 packed stores.
// ---------------------------------------------------------------------------
__global__ __launch_bounds__(256) void transpose_x2(
    const float* __restrict__ x, unsigned short* __restrict__ xt) {
  __shared__ float t[64][65];
  const int tid = threadIdx.x;
  const int n0 = blockIdx.x * 64, c0 = blockIdx.y * 64, b = blockIdx.z;
  const float* xb = x + ((long)b * kD + c0) * kN + n0;
#pragma unroll
  for (int r = 0; r < 4; ++r) {
    const int idx = tid + r * 256;  // 1024 float4 total
    const int c = idx >> 4, n4 = (idx & 15) * 4;
    const float4 v = *(const float4*)(xb + (long)c * kN + n4);
    t[c][n4] = v.x; t[c][n4 + 1] = v.y; t[c][n4 + 2] = v.z; t[c][n4 + 3] = v.w;
  }
  __syncthreads();
  unsigned short* xtb = xt + ((long)b * kN + n0) * kD + c0;
#pragma unroll
  for (int r = 0; r < 4; ++r) {
    const int idx = tid + r * 256;
    const int n = idx >> 4, cg = (idx & 15) * 4;
    ushort4 o;
    o.x = f2bf(t[cg + 0][n]); o.y = f2bf(t[cg + 1][n]);
    o.z = f2bf(t[cg + 2][n]); o.w = f2bf(t[cg + 3][n]);
    *(ushort4*)&xtb[(long)n * kD + cg] = o;
  }
}

// ---------------------------------------------------------------------------
// Fused qkv GEMM + feature map. Block: 256 channels (one of q/k/v) x 64 px.
// LDS tiles in K-major layout [ks][row][8] -> conflict-free ds_read_b128.
// Double-buffered, one barrier per K-step (prefetch overlaps MFMA).
// type 0 (q): feature-map, write qt[n][c] bf16 (transposed)
// type 1 (k): feature-map, write kb[c][n] bf16, fused kmean atomicAdd
// type 2 (v): bias only,  write vb[c][n] bf16
// ---------------------------------------------------------------------------
__global__ __launch_bounds__(256) void qkv5_mfma(
    const unsigned short* __restrict__ Wb, const unsigned short* __restrict__ xt,
    const float* __restrict__ bias, unsigned short* __restrict__ qt,
    unsigned short* __restrict__ kb, unsigned short* __restrict__ vb,
    float* __restrict__ km) {
  __shared__ unsigned short sA[2][256 * 32] __attribute__((aligned(16)));
  __shared__ unsigned short sB[2][64 * 32] __attribute__((aligned(16)));
  __shared__ float sBias[256];
  __shared__ float colbuf[4][64];
  const int tid = threadIdx.x;
  const int n0 = blockIdx.x * 64, type = blockIdx.y, b = blockIdx.z;
  const int m0 = type * 256;
  const unsigned short* xtb = xt + (long)b * kN * kD;
  const int lane = tid & 63, w = tid >> 6;
  const int lr = lane & 15, lq = lane >> 4;
  sBias[tid] = bias[m0 + tid];

  f32x4 acc[4][4];
#pragma unroll
  for (int i = 0; i < 4; ++i)
#pragma unroll
    for (int j = 0; j < 4; ++j) acc[i][j] = (f32x4){0.f, 0.f, 0.f, 0.f};

  // prologue: stage K-step 0 into buf 0 (K-major chunk mapping)
#pragma unroll
  for (int r = 0; r < 4; ++r) {
    const int c = tid + r * 256;            // A: 1024 chunks
    const int row = c & 255, ks = c >> 8;
    gl_lds16(Wb + (long)(m0 + row) * 256 + 0 + ks * 8, &sA[0][c * 8]);
  }
  {
    const int c = tid;                      // B: 256 chunks
    const int row = c & 63, ks = c >> 6;
    gl_lds16(xtb + (long)(n0 + row) * kD + 0 + ks * 8, &sB[0][c * 8]);
  }
  __syncthreads();

  for (int kk = 0; kk < 8; ++kk) {
    const int cur = kk & 1;
    if (kk < 7) {
      const int k0 = (kk + 1) * 32;
#pragma unroll
      for (int r = 0; r < 4; ++r) {
        const int c = tid + r * 256;
        const int row = c & 255, ks = c >> 8;
        gl_lds16(Wb + (long)(m0 + row) * 256 + k0 + ks * 8,
                 &sA[cur ^ 1][c * 8]);
      }
      {
        const int c = tid;
        const int row = c & 63, ks = c >> 6;
        gl_lds16(xtb + (long)(n0 + row) * kD + k0 + ks * 8,
                 &sB[cur ^ 1][c * 8]);
      }
    }
    bf16x8 af[4], bfr[4];
#pragma unroll
    for (int mt = 0; mt < 4; ++mt)
      af[mt] = *(const bf16x8*)&sA[cur][(lq * 256 + w * 64 + mt * 16 + lr) * 8];
#pragma unroll
    for (int nt = 0; nt < 4; ++nt)
      bfr[nt] = *(const bf16x8*)&sB[cur][(lq * 64 + nt * 16 + lr) * 8];
#pragma unroll
    for (int mt = 0; mt < 4; ++mt)
#pragma unroll
      for (int nt = 0; nt < 4; ++nt)
        acc[mt][nt] = __builtin_amdgcn_mfma_f32_16x16x32_bf16(
            af[mt], bfr[nt], acc[mt][nt], 0, 0, 0);
    __syncthreads();
  }

  if (type < 2) {
    float part[4] = {0.f, 0.f, 0.f, 0.f};
#pragma unroll
    for (int mt = 0; mt < 4; ++mt) {
#pragma unroll
      for (int rr = 0; rr < 4; ++rr) {
        const float bv = sBias[w * 64 + mt * 16 + lq * 4 + rr];
#pragma unroll
        for (int nt = 0; nt < 4; ++nt) {
          const float r_ = fmaxf(acc[mt][nt][rr] + bv, 0.f) + FLA_EPS;
          const float t = r_ * r_;
          acc[mt][nt][rr] = t;
          part[nt] += t * t;
        }
      }
    }
#pragma unroll
    for (int nt = 0; nt < 4; ++nt) {
      part[nt] += __shfl_xor(part[nt], 16);
      part[nt] += __shfl_xor(part[nt], 32);
    }
    if (lq == 0)
#pragma unroll
      for (int nt = 0; nt < 4; ++nt) colbuf[w][nt * 16 + lr] = part[nt];
    __syncthreads();
    float inv[4];
#pragma unroll
    for (int nt = 0; nt < 4; ++nt) {
      const int col = nt * 16 + lr;
      const float S = colbuf[0][col] + colbuf[1][col] + colbuf[2][col] + colbuf[3][col];
      inv[nt] = 1.f / fmaxf(sqrtf(S), 1e-12f);
    }
    if (type == 0) {  // qt[n][c]
      unsigned short* qtb = qt + (long)b * kN * kD;
#pragma unroll
      for (int mt = 0; mt < 4; ++mt)
#pragma unroll
        for (int nt = 0; nt < 4; ++nt) {
          ushort4 o;
          o.x = f2bf(acc[mt][nt][0] * inv[nt]);
          o.y = f2bf(acc[mt][nt][1] * inv[nt]);
          o.z = f2bf(acc[mt][nt][2] * inv[nt]);
          o.w = f2bf(acc[mt][nt][3] * inv[nt]);
          *(ushort4*)&qtb[(long)(n0 + nt * 16 + lr) * kD + w * 64 + mt * 16 + lq * 4] = o;
        }
    } else {  // kb[c][n] + fused kmean
      unsigned short* kbb = kb + (long)b * kD * kN;
#pragma unroll
      for (int mt = 0; mt < 4; ++mt)
#pragma unroll
        for (int rr = 0; rr < 4; ++rr) {
          const int ch = w * 64 + mt * 16 + lq * 4 + rr;
          float ks = 0.f;
#pragma unroll
          for (int nt = 0; nt < 4; ++nt) {
            const unsigned short sv = f2bf(acc[mt][nt][rr] * inv[nt]);
            kbb[(long)ch * kN + n0 + nt * 16 + lr] = sv;
            ks += bf2f(sv);
          }
          ks += __shfl_xor(ks, 1);
          ks += __shfl_xor(ks, 2);
          ks += __shfl_xor(ks, 4);
          ks += __shfl_xor(ks, 8);
          if (lr == 0) atomicAdd(&km[b * kD + ch], ks * (1.f / kN));
        }
    }
  } else {  // v: bias only -> vb[c][n]
    unsigned short* vbb = vb + (long)b * kD * kN;
#pragma unroll
    for (int mt = 0; mt < 4; ++mt)
#pragma unroll
      for (int rr = 0; rr < 4; ++rr) {
        const int ch = w * 64 + mt * 16 + lq * 4 + rr;
        const float bv = sBias[ch];
#pragma unroll
        for (int nt = 0; nt < 4; ++nt)
          vbb[(long)ch * kN + n0 + nt * 16 + lr] = f2bf(acc[mt][nt][rr] + bv);
      }
  }
}

// ---------------------------------------------------------------------------
// Tpart[s][b][i][j] = sum_{n in slice s} vb[i][n] * kb[j][n]
// K-major LDS, double-buffered, one barrier per K-step.
// ---------------------------------------------------------------------------
__global__ __launch_bounds__(256) void vkt3_mfma(
    const unsigned short* __restrict__ vb, const unsigned short* __restrict__ kb,
    float* __restrict__ Tpart) {
  __shared__ unsigned short sA[2][128 * 32] __attribute__((aligned(16)));
  __shared__ unsigned short sB[2][128 * 32] __attribute__((aligned(16)));
  const int tid = threadIdx.x;
  const int i0 = blockIdx.x * 128, j0 = blockIdx.y * 128;
  const int b = blockIdx.z >> 3, s = blockIdx.z & 7;
  const unsigned short* vbb = vb + (long)b * kD * kN;
  const unsigned short* kbb = kb + (long)b * kD * kN;
  const int lane = tid & 63, w = tid >> 6;
  const int wm = (w & 1) * 64, wn = (w >> 1) * 64;
  const int lr = lane & 15, lq = lane >> 4;
  const int c0 = tid, c1 = 256 + tid;
  const int r0 = c0 & 127, s0 = c0 >> 7;
  const int r1 = c1 & 127, s1 = c1 >> 7;

  f32x4 acc[4][4];
#pragma unroll
  for (int i = 0; i < 4; ++i)
#pragma unroll
    for (int j = 0; j < 4; ++j) acc[i][j] = (f32x4){0.f, 0.f, 0.f, 0.f};

  const int nbase = s * 512;
  gl_lds16(vbb + (long)(i0 + r0) * kN + nbase + s0 * 8, &sA[0][c0 * 8]);
  gl_lds16(vbb + (long)(i0 + r1) * kN + nbase + s1 * 8, &sA[0][c1 * 8]);
  gl_lds16(kbb + (long)(j0 + r0) * kN + nbase + s0 * 8, &sB[0][c0 * 8]);
  gl_lds16(kbb + (long)(j0 + r1) * kN + nbase + s1 * 8, &sB[0][c1 * 8]);
  __syncthreads();

  for (int kk = 0; kk < 16; ++kk) {
    const int cur = kk & 1;
    if (kk < 15) {
      const int n0 = nbase + (kk + 1) * 32;
      gl_lds16(vbb + (long)(i0 + r0) * kN + n0 + s0 * 8, &sA[cur ^ 1][c0 * 8]);
      gl_lds16(vbb + (long)(i0 + r1) * kN + n0 + s1 * 8, &sA[cur ^ 1][c1 * 8]);
      gl_lds16(kbb + (long)(j0 + r0) * kN + n0 + s0 * 8, &sB[cur ^ 1][c0 * 8]);
      gl_lds16(kbb + (long)(j0 + r1) * kN + n0 + s1 * 8, &sB[cur ^ 1][c1 * 8]);
    }
    bf16x8 af[4], bf[4];
#pragma unroll
    for (int mt = 0; mt < 4; ++mt)
      af[mt] = *(const bf16x8*)&sA[cur][(lq * 128 + wm + mt * 16 + lr) * 8];
#pragma unroll
    for (int nt = 0; nt < 4; ++nt)
      bf[nt] = *(const bf16x8*)&sB[cur][(lq * 128 + wn + nt * 16 + lr) * 8];
#pragma unroll
    for (int mt = 0; mt < 4; ++mt)
#pragma unroll
      for (int nt = 0; nt < 4; ++nt)
        acc[mt][nt] = __builtin_amdgcn_mfma_f32_16x16x32_bf16(
            af[mt], bf[nt], acc[mt][nt], 0, 0, 0);
    __syncthreads();
  }
  float* Tp = Tpart + ((long)s * kB + b) * kD * kD;
#pragma unroll
  for (int mt = 0; mt < 4; ++mt)
#pragma unroll
    for (int nt = 0; nt < 4; ++nt) {
      const int j = j0 + wn + nt * 16 + lr;
#pragma unroll
      for (int r = 0; r < 4; ++r) {
        const int i = i0 + wm + mt * 16 + lq * 4 + r;
        Tp[(long)i * kD + j] = acc[mt][nt][r];
      }
    }
}

// ---------------------------------------------------------------------------
// Tt[b][i][j] bf16 = (1/N) * sum_s Tpart[s][b][i][j]
// ---------------------------------------------------------------------------
__global__ __launch_bounds__(256) void tconvert(
    const float* __restrict__ Tpart, unsigned short* __restrict__ Tt) {
  const long idx = (long)blockIdx.x * 256 + threadIdx.x;
  float s = 0.f;
#pragma unroll
  for (int p = 0; p < 8; ++p) s += Tpart[(long)p * 1048576 + idx];
  Tt[idx] = f2bf(s * (1.f / 4096.f));
}

// ---------------------------------------------------------------------------
// Depthwise 5x5 conv: vb bf16 -> dwp bf16 (incl. bias).
// ---------------------------------------------------------------------------
__global__ __launch_bounds__(256) void dwconv3(
    const unsigned short* __restrict__ vb, const float* __restrict__ dwc_w,
    const float* __restrict__ dwc_b, unsigned short* __restrict__ dwp) {
  __shared__ float tile[68][80];
  __shared__ float wt[32];
  const int c = blockIdx.x, b = blockIdx.y;
  const int tid = threadIdx.x;
  if (tid < 25) wt[tid] = dwc_w[c * 25 + tid];
  {  // zero the whole tile (simple halo init): 68*80/4 = 1360 float4
    const float4 z4 = {0.f, 0.f, 0.f, 0.f};
    float* tf = &tile[0][0];
#pragma unroll
    for (int r = 0; r < 6; ++r) {
      const int i = tid + r * 256;
      if (i < 1360) *(float4*)(tf + i * 4) = z4;
    }
  }
  __syncthreads();
  const unsigned short* vp = vb + ((long)b * kD + c) * kN;
#pragma unroll
  for (int r = 0; r < 2; ++r) {  // 512 uint4 chunks (8 bf16 each)
    const int ch = tid + r * 256;
    const int row = ch >> 3, sub = ch & 7;
    const uint4 u = *(const uint4*)(vp + row * 64 + sub * 8);
    const unsigned short* p = (const unsigned short*)&u;
    float4 f0, f1;
    f0.x = bf2f(p[0]); f0.y = bf2f(p[1]); f0.z = bf2f(p[2]); f0.w = bf2f(p[3]);
    f1.x = bf2f(p[4]); f1.y = bf2f(p[5]); f1.z = bf2f(p[6]); f1.w = bf2f(p[7]);
    *(float4*)&tile[row + 2][4 + sub * 8] = f0;
    *(float4*)&tile[row + 2][8 + sub * 8] = f1;
  }
  __syncthreads();
  float w_[25];
#pragma unroll
  for (int i = 0; i < 25; ++i) w_[i] = wt[i];
  const float bias = dwc_b[c];
  const int pr = tid >> 4, pc = tid & 15;
  const int oy0 = pr * 4, ox0 = pc * 4;
  float win[8][12];
#pragma unroll
  for (int r = 0; r < 8; ++r) {
    *(float4*)&win[r][0] = *(const float4*)&tile[oy0 + r][ox0 + 0];
    *(float4*)&win[r][4] = *(const float4*)&tile[oy0 + r][ox0 + 4];
    *(float4*)&win[r][8] = *(const float4*)&tile[oy0 + r][ox0 + 8];
  }
  unsigned short* yp = dwp + ((long)b * kD + c) * kN;
#pragma unroll
  for (int dy = 0; dy < 4; ++dy) {
    ushort4 o;
    unsigned short* op = (unsigned short*)&o;
#pragma unroll
    for (int dx = 0; dx < 4; ++dx) {
      float s = bias;
#pragma unroll
      for (int ky = 0; ky < 5; ++ky)
#pragma unroll
        for (int kx = 0; kx < 5; ++kx)
          s += win[dy + ky][dx + kx + 2] * w_[ky * 5 + kx];
      op[dx] = f2bf(s);
    }
    *(ushort4*)&yp[(oy0 + dy) * 64 + ox0] = o;
  }
}

// ---------------------------------------------------------------------------
// attn: D[pix][ch] = sum_j qt[n][j] Tt[ch][j]; fused z (kmean.q), /z,
// RMSNorm over ch, *norm_w, + dw  -> yt[n][ch] bf16.
// K-major LDS, double-buffered, one barrier per K-step.
// ---------------------------------------------------------------------------
__global__ __launch_bounds__(256) void attn3_mfma(
    const unsigned short* __restrict__ qt, const unsigned short* __restrict__ Tt,
    const float* __restrict__ kmean, const float* __restrict__ norm_w,
    const unsigned short* __restrict__ dwp, unsigned short* __restrict__ yt) {
  __shared__ unsigned char smem[40960] __attribute__((aligned(16)));
  __shared__ float sKm[256];
  __shared__ float sNw[256];
  __shared__ float zbuf[64];
  __shared__ float rbuf[4][64];
  // buf layout: [buf][sQ 4096B][sT 16384B], buf stride 20480B
  unsigned short* sDw = (unsigned short*)smem;  // 256 x 72 (reuse after loop)
  const int tid = threadIdx.x;
  const int n0 = blockIdx.x * 64, b = blockIdx.y;
  const unsigned short* qtb = qt + (long)b * kN * kD;
  const unsigned short* Ttb = Tt + (long)b * kD * kD;
  sKm[tid] = kmean[b * kD + tid];
  sNw[tid] = norm_w[tid];
  const int lane = tid & 63, w = tid >> 6;
  const int lr = lane & 15, lq = lane >> 4;

  f32x4 acc[4][4];
#pragma unroll
  for (int i = 0; i < 4; ++i)
#pragma unroll
    for (int j = 0; j < 4; ++j) acc[i][j] = (f32x4){0.f, 0.f, 0.f, 0.f};
  float zp[4] = {0.f, 0.f, 0.f, 0.f};

  // prologue: stage K-step 0
  {
    unsigned short* sQ = (unsigned short*)(smem);
    unsigned short* sT = (unsigned short*)(smem + 4096);
    {
      const int c = tid, row = c & 63, ks = c >> 6;
      gl_lds16(qtb + (long)(n0 + row) * kD + 0 + ks * 8, &sQ[c * 8]);
    }
#pragma unroll
    for (int r = 0; r < 4; ++r) {
      const int c = tid + r * 256, row = c & 255, ks = c >> 8;
      gl_lds16(Ttb + (long)row * kD + 0 + ks * 8, &sT[c * 8]);
    }
  }
  __syncthreads();

  for (int kk = 0; kk < 8; ++kk) {
    const int cur = kk & 1;
    unsigned short* sQ = (unsigned short*)(smem + cur * 20480);
    unsigned short* sT = (unsigned short*)(smem + cur * 20480 + 4096);
    if (kk < 7) {
      const int k0 = (kk + 1) * 32;
      unsigned short* nQ = (unsigned short*)(smem + (cur ^ 1) * 20480);
      unsigned short* nT = (unsigned short*)(smem + (cur ^ 1) * 20480 + 4096);
      {
        const int c = tid, row = c & 63, ks = c >> 6;
        gl_lds16(qtb + (long)(n0 + row) * kD + k0 + ks * 8, &nQ[c * 8]);
      }
#pragma unroll
      for (int r = 0; r < 4; ++r) {
        const int c = tid + r * 256, row = c & 255, ks = c >> 8;
        gl_lds16(Ttb + (long)row * kD + k0 + ks * 8, &nT[c * 8]);
      }
    }
    bf16x8 af[4], bf[4];
#pragma unroll
    for (int mt = 0; mt < 4; ++mt)
      af[mt] = *(const bf16x8*)&sQ[(lq * 64 + mt * 16 + lr) * 8];
#pragma unroll
    for (int nt = 0; nt < 4; ++nt)
      bf[nt] = *(const bf16x8*)&sT[(lq * 256 + w * 64 + nt * 16 + lr) * 8];
#pragma unroll
    for (int mt = 0; mt < 4; ++mt)
#pragma unroll
      for (int j = 0; j < 8; ++j)
        zp[mt] += bf2f((unsigned short)af[mt][j]) * sKm[kk * 32 + lq * 8 + j];
#pragma unroll
    for (int mt = 0; mt < 4; ++mt)
#pragma unroll
      for (int nt = 0; nt < 4; ++nt)
        acc[mt][nt] = __builtin_amdgcn_mfma_f32_16x16x32_bf16(
            af[mt], bf[nt], acc[mt][nt], 0, 0, 0);
    __syncthreads();
  }

  const unsigned short* dwpb = dwp + (long)b * kD * kN;
#pragma unroll
  for (int it = 0; it < 8; ++it) {
    const int c = tid + it * 256;
    const int row = c >> 3, sub = c & 7;
    uint4 t4 = *(const uint4*)(dwpb + (long)row * kN + n0 + sub * 8);
    *(uint4*)&sDw[row * 72 + sub * 8] = t4;
  }
#pragma unroll
  for (int mt = 0; mt < 4; ++mt) {
    zp[mt] += __shfl_xor(zp[mt], 16);
    zp[mt] += __shfl_xor(zp[mt], 32);
  }
  if (w == 0 && lq == 0)
#pragma unroll
    for (int mt = 0; mt < 4; ++mt) zbuf[mt * 16 + lr] = zp[mt];
  __syncthreads();

  float ss[4][4];
#pragma unroll
  for (int mt = 0; mt < 4; ++mt)
#pragma unroll
    for (int r = 0; r < 4; ++r) {
      const float invz = 1.f / (zbuf[mt * 16 + lq * 4 + r] + FLA_EPS);
      float s = 0.f;
#pragma unroll
      for (int nt = 0; nt < 4; ++nt) {
        acc[mt][nt][r] *= invz;
        s += acc[mt][nt][r] * acc[mt][nt][r];
      }
      ss[mt][r] = s;
    }
#pragma unroll
  for (int mt = 0; mt < 4; ++mt)
#pragma unroll
    for (int r = 0; r < 4; ++r) {
      ss[mt][r] += __shfl_xor(ss[mt][r], 1);
      ss[mt][r] += __shfl_xor(ss[mt][r], 2);
      ss[mt][r] += __shfl_xor(ss[mt][r], 4);
      ss[mt][r] += __shfl_xor(ss[mt][r], 8);
    }
  if (lr == 0)
#pragma unroll
    for (int mt = 0; mt < 4; ++mt)
#pragma unroll
      for (int r = 0; r < 4; ++r) rbuf[w][mt * 16 + lq * 4 + r] = ss[mt][r];
  __syncthreads();

  unsigned short* ytb = yt + (long)b * kN * kD;
  float nw[4];
#pragma unroll
  for (int nt = 0; nt < 4; ++nt) nw[nt] = sNw[w * 64 + nt * 16 + lr];
#pragma unroll
  for (int mt = 0; mt < 4; ++mt)
#pragma unroll
    for (int r = 0; r < 4; ++r) {
      const int p = mt * 16 + lq * 4 + r;
      const float S = rbuf[0][p] + rbuf[1][p] + rbuf[2][p] + rbuf[3][p];
      const float scl = rsqrtf(S * (1.f / 256.f) + FLA_EPS);
#pragma unroll
      for (int nt = 0; nt < 4; ++nt) {
        const int ch = w * 64 + nt * 16 + lr;
        const float dw = bf2f(sDw[ch * 72 + p]);
        const float o = acc[mt][nt][r] * scl * nw[nt] + dw;
        ytb[(long)(n0 + p) * kD + ch] = f2bf(o);
      }
    }
}

// ---------------------------------------------------------------------------
// proj: out[b][c][n] = proj_w @ yt^T + proj_b  (MFMA, fp32 out)
// K-major LDS, double-buffered, one barrier per K-step.
// ---------------------------------------------------------------------------
__global__ __launch_bounds__(256) void proj3_mfma(
    const unsigned short* __restrict__ Wb, const unsigned short* __restrict__ yt,
    const float* __restrict__ bias, float* __restrict__ out) {
  __shared__ unsigned short sA[2][128 * 32] __attribute__((aligned(16)));
  __shared__ unsigned short sB[2][128 * 32] __attribute__((aligned(16)));
  const int tid = threadIdx.x;
  const int n0 = blockIdx.x * 128, m0 = blockIdx.y * 128, b = blockIdx.z;
  const unsigned short* ytb = yt + (long)b * kN * kD;
  const int lane = tid & 63, w = tid >> 6;
  const int wm = (w & 1) * 64, wn = (w >> 1) * 64;
  const int lr = lane & 15, lq = lane >> 4;
  const int c0 = tid, c1 = 256 + tid;
  const int r0 = c0 & 127, s0 = c0 >> 7;
  const int r1 = c1 & 127, s1 = c1 >> 7;

  f32x4 acc[4][4];
#pragma unroll
  for (int i = 0; i < 4; ++i)
#pragma unroll
    for (int j = 0; j < 4; ++j) acc[i][j] = (f32x4){0.f, 0.f, 0.f, 0.f};

  gl_lds16(Wb + (long)(m0 + r0) * kD + 0 + s0 * 8, &sA[0][c0 * 8]);
  gl_lds16(Wb + (long)(m0 + r1) * kD + 0 + s1 * 8, &sA[0][c1 * 8]);
  gl_lds16(ytb + (long)(n0 + r0) * kD + 0 + s0 * 8, &sB[0][c0 * 8]);
  gl_lds16(ytb + (long)(n0 + r1) * kD + 0 + s1 * 8, &sB[0][c1 * 8]);
  __syncthreads();

  for (int kk = 0; kk < 8; ++kk) {
    const int cur = kk & 1;
    if (kk < 7) {
      const int k0 = (kk + 1) * 32;
      gl_lds16(Wb + (long)(m0 + r0) * kD + k0 + s0 * 8, &sA[cur ^ 1][c0 * 8]);
      gl_lds16(Wb + (long)(m0 + r1) * kD + k0 + s1 * 8, &sA[cur ^ 1][c1 * 8]);
      gl_lds16(ytb + (long)(n0 + r0) * kD + k0 + s0 * 8, &sB[cur ^ 1][c0 * 8]);
      gl_lds16(ytb + (long)(n0 + r1) * kD + k0 + s1 * 8, &sB[cur ^ 1][c1 * 8]);
    }
    bf16x8 af[4], bf[4];
#pragma unroll
    for (int mt = 0; mt < 4; ++mt)
      af[mt] = *(const bf16x8*)&sA[cur][(lq * 128 + wm + mt * 16 + lr) * 8];
#pragma unroll
    for (int nt = 0; nt < 4; ++nt)
      bf[nt] = *(const bf16x8*)&sB[cur][(lq * 128 + wn + nt * 16 + lr) * 8];
#pragma unroll
    for (int mt = 0; mt < 4; ++mt)
#pragma unroll
      for (int nt = 0; nt < 4; ++nt)
        acc[mt][nt] = __builtin_amdgcn_mfma_f32_16x16x32_bf16(
            af[mt], bf[nt], acc[mt][nt], 0, 0, 0);
    __syncthreads();
  }
  float* ob = out + (long)b * kD * kN;
#pragma unroll
  for (int mt = 0; mt < 4; ++mt)
#pragma unroll
    for (int nt = 0; nt < 4; ++nt) {
      const int n = n0 + wn + nt * 16 + lr;
#pragma unroll
      for (int r = 0; r < 4; ++r) {
        const int m = m0 + wm + mt * 16 + lq * 4 + r;
        ob[(long)m * kN + n] = acc[mt][nt][r] + bias[m];
      }
    }
}

// ---------------------------------------------------------------------------
extern "C" void kernel_launch(void* const* d_in, const int* in_sizes, int n_in,
                              void* d_out, int out_size, void* d_ws,
                              size_t ws_size, hipStream_t stream) {
  const float* x      = (const float*)d_in[0];
  const float* qkv_w  = (const float*)d_in[1];
  const float* qkv_b  = (const float*)d_in[2];
  const float* dwc_w  = (const float*)d_in[3];
  const float* dwc_b  = (const float*)d_in[4];
  const float* norm_w = (const float*)d_in[5];
  const float* proj_w = (const float*)d_in[6];
  const float* proj_b = (const float*)d_in[7];
  float* out = (float*)d_out;
  char* ws = (char*)d_ws;

  constexpr long SZ = 33554432;  // 16*4096*256 * 2B
  unsigned short* qt  = (unsigned short*)(ws);
  unsigned short* kb  = (unsigned short*)(ws + SZ);
  unsigned short* vb  = (unsigned short*)(ws + 2 * SZ);
  unsigned short* dwp = (unsigned short*)(ws + 3 * SZ);
  unsigned short* yt  = (unsigned short*)(ws + 4 * SZ);
  unsigned short* xt  = (unsigned short*)(ws + 5 * SZ);
  float* Tpart        = (float*)(ws + 5 * SZ);        // aliases xt (dead)
  unsigned short* Tt  = (unsigned short*)(ws + 6 * SZ);
  unsigned short* wqb = (unsigned short*)(ws + 6 * SZ + 2097152);
  unsigned short* wpb = (unsigned short*)(ws + 6 * SZ + 2097152 + 393216);
  float* km           = (float*)(ws + 6 * SZ + 2097152 + 393216 + 131072);

  convert_w<<<768, 256, 0, stream>>>(qkv_w, wqb, kO3 * kD);
  convert_w<<<256, 256, 0, stream>>>(proj_w, wpb, kD * kD);
  transpose_x2<<<dim3(64, 4, 16), 256, 0, stream>>>(x, xt);
  hipMemsetAsync(km, 0, kB * kD * sizeof(float), stream);  // fused kmean accum
  qkv5_mfma<<<dim3(64, 3, 16), 256, 0, stream>>>(wqb, xt, qkv_b, qt, kb, vb, km);
  vkt3_mfma<<<dim3(2, 2, 128), 256, 0, stream>>>(vb, kb, Tpart);
  tconvert<<<4096, 256, 0, stream>>>(Tpart, Tt);
  dwconv3<<<dim3(256, 16), 256, 0, stream>>>(vb, dwc_w, dwc_b, dwp);
  attn3_mfma<<<dim3(64, 16), 256, 0, stream>>>(qt, Tt, km, norm_w, dwp, yt);
  proj3_mfma<<<dim3(32, 2, 16), 256, 0, stream>>>(wpb, yt, proj_b, out);
}

// Round 3
// 302.311 us; speedup vs baseline: 1.3078x; 1.1881x over previous
//
#include <hip/hip_runtime.h>
#include <math.h>
#include <stdint.h>

#define FLA_EPS 1e-5f

constexpr int kB  = 16;
constexpr int kD  = 256;   // d == C == 256
constexpr int kN  = 4096;  // H*W
constexpr int kO3 = 768;   // 3*d

typedef __attribute__((ext_vector_type(8))) short bf16x8;
typedef __attribute__((ext_vector_type(4))) float f32x4;

__device__ __forceinline__ unsigned short f2bf(float f) {
  union { float f; uint32_t u; } v; v.f = f;
  uint32_t r = v.u + 0x7FFFu + ((v.u >> 16) & 1u);  // RNE
  return (unsigned short)(r >> 16);
}
__device__ __forceinline__ float bf2f(unsigned short h) {
  union { uint32_t u; float f; } v; v.u = ((uint32_t)h) << 16; return v.f;
}
__device__ __forceinline__ void gl_lds16(const void* g, void* l) {
  __builtin_amdgcn_global_load_lds(
      (const __attribute__((address_space(1))) uint32_t*)g,
      (__attribute__((address_space(3))) uint32_t*)l, 16, 0, 0);
}

// Staging-side k-slice swizzle for chunk c with row=c>>2, ks=c&3:
//   source k-slice = ks ^ ((row>>1)&3)  == (c&3) ^ ((c>>3)&3)
// Read-side: fragment for k-slice lq of row lives at chunk lq ^ ((row>>1)&3);
// since rows are base+lr with base%16==0, (row>>1)&3 == (lr>>1)&3.
#define SWZ_SRC(c) (((c) & 3) ^ (((c) >> 3) & 3))

// ---------------------------------------------------------------------------
// fp32 -> bf16 weight convert
// ---------------------------------------------------------------------------
__global__ __launch_bounds__(256) void convert_w(
    const float* __restrict__ w, unsigned short* __restrict__ wb, int n) {
  const int i = blockIdx.x * 256 + threadIdx.x;
  if (i < n) wb[i] = f2bf(w[i]);
}

// ---------------------------------------------------------------------------
// x [B][C][N] fp32 -> xt [B][N][C] bf16. 64x64 tiles, float4 loads,
// ushort4 packed stores.
// ---------------------------------------------------------------------------
__global__ __launch_bounds__(256) void transpose_x2(
    const float* __restrict__ x, unsigned short* __restrict__ xt) {
  __shared__ float t[64][65];
  const int tid = threadIdx.x;
  const int n0 = blockIdx.x * 64, c0 = blockIdx.y * 64, b = blockIdx.z;
  const float* xb = x + ((long)b * kD + c0) * kN + n0;
#pragma unroll
  for (int r = 0; r < 4; ++r) {
    const int idx = tid + r * 256;  // 1024 float4 total
    const int c = idx >> 4, n4 = (idx & 15) * 4;
    const float4 v = *(const float4*)(xb + (long)c * kN + n4);
    t[c][n4] = v.x; t[c][n4 + 1] = v.y; t[c][n4 + 2] = v.z; t[c][n4 + 3] = v.w;
  }
  __syncthreads();
  unsigned short* xtb = xt + ((long)b * kN + n0) * kD + c0;
#pragma unroll
  for (int r = 0; r < 4; ++r) {
    const int idx = tid + r * 256;
    const int n = idx >> 4, cg = (idx & 15) * 4;
    ushort4 o;
    o.x = f2bf(t[cg + 0][n]); o.y = f2bf(t[cg + 1][n]);
    o.z = f2bf(t[cg + 2][n]); o.w = f2bf(t[cg + 3][n]);
    *(ushort4*)&xtb[(long)n * kD + cg] = o;
  }
}

// ---------------------------------------------------------------------------
// Fused qkv GEMM + feature map. Block: 256 channels (one of q/k/v) x 64 pix.
// Round-0 structure (2 barriers/K-step) + k-slice XOR swizzle (conflict-free
// ds_read_b128, source coalescing preserved).
// type 0 (q): feature-map, write qt[n][c] bf16 (transposed)
// type 1 (k): feature-map, write kb[c][n] bf16, fused kmean atomicAdd
// type 2 (v): bias only,  write vb[c][n] bf16
// ---------------------------------------------------------------------------
__global__ __launch_bounds__(256) void qkv6_mfma(
    const unsigned short* __restrict__ Wb, const unsigned short* __restrict__ xt,
    const float* __restrict__ bias, unsigned short* __restrict__ qt,
    unsigned short* __restrict__ kb, unsigned short* __restrict__ vb,
    float* __restrict__ km) {
  __shared__ unsigned short sA[256 * 32] __attribute__((aligned(16)));
  __shared__ unsigned short sB[64 * 32] __attribute__((aligned(16)));
  __shared__ float sBias[256];
  __shared__ float colbuf[4][64];
  const int tid = threadIdx.x;
  const int n0 = blockIdx.x * 64, type = blockIdx.y, b = blockIdx.z;
  const int m0 = type * 256;
  const unsigned short* xtb = xt + (long)b * kN * kD;
  const int lane = tid & 63, w = tid >> 6;
  const int lr = lane & 15, lq = lane >> 4;
  const int sxk = (lq ^ ((lr >> 1) & 3)) * 8;  // swizzled k-slice elem offset
  sBias[tid] = bias[m0 + tid];

  f32x4 acc[4][4];
#pragma unroll
  for (int i = 0; i < 4; ++i)
#pragma unroll
    for (int j = 0; j < 4; ++j) acc[i][j] = (f32x4){0.f, 0.f, 0.f, 0.f};

  for (int k0 = 0; k0 < 256; k0 += 32) {
#pragma unroll
    for (int r = 0; r < 4; ++r) {  // A: 256 rows x 32k = 1024 chunks
      const int c = tid + r * 256;
      gl_lds16(Wb + (long)(m0 + (c >> 2)) * 256 + k0 + SWZ_SRC(c) * 8,
               &sA[c * 8]);
    }
    {  // B: 64 rows x 32k = 256 chunks
      const int c = tid;
      gl_lds16(xtb + (long)(n0 + (c >> 2)) * kD + k0 + SWZ_SRC(c) * 8,
               &sB[c * 8]);
    }
    __syncthreads();
    bf16x8 af[4], bfr[4];
#pragma unroll
    for (int mt = 0; mt < 4; ++mt)
      af[mt] = *(const bf16x8*)&sA[(w * 64 + mt * 16 + lr) * 32 + sxk];
#pragma unroll
    for (int nt = 0; nt < 4; ++nt)
      bfr[nt] = *(const bf16x8*)&sB[(nt * 16 + lr) * 32 + sxk];
#pragma unroll
    for (int mt = 0; mt < 4; ++mt)
#pragma unroll
      for (int nt = 0; nt < 4; ++nt)
        acc[mt][nt] = __builtin_amdgcn_mfma_f32_16x16x32_bf16(
            af[mt], bfr[nt], acc[mt][nt], 0, 0, 0);
    __syncthreads();
  }

  if (type < 2) {
    float part[4] = {0.f, 0.f, 0.f, 0.f};
#pragma unroll
    for (int mt = 0; mt < 4; ++mt) {
#pragma unroll
      for (int rr = 0; rr < 4; ++rr) {
        const float bv = sBias[w * 64 + mt * 16 + lq * 4 + rr];
#pragma unroll
        for (int nt = 0; nt < 4; ++nt) {
          const float r_ = fmaxf(acc[mt][nt][rr] + bv, 0.f) + FLA_EPS;
          const float t = r_ * r_;
          acc[mt][nt][rr] = t;
          part[nt] += t * t;
        }
      }
    }
#pragma unroll
    for (int nt = 0; nt < 4; ++nt) {
      part[nt] += __shfl_xor(part[nt], 16);
      part[nt] += __shfl_xor(part[nt], 32);
    }
    if (lq == 0)
#pragma unroll
      for (int nt = 0; nt < 4; ++nt) colbuf[w][nt * 16 + lr] = part[nt];
    __syncthreads();
    float inv[4];
#pragma unroll
    for (int nt = 0; nt < 4; ++nt) {
      const int col = nt * 16 + lr;
      const float S = colbuf[0][col] + colbuf[1][col] + colbuf[2][col] + colbuf[3][col];
      inv[nt] = 1.f / fmaxf(sqrtf(S), 1e-12f);
    }
    if (type == 0) {  // qt[n][c]
      unsigned short* qtb = qt + (long)b * kN * kD;
#pragma unroll
      for (int mt = 0; mt < 4; ++mt)
#pragma unroll
        for (int nt = 0; nt < 4; ++nt) {
          ushort4 o;
          o.x = f2bf(acc[mt][nt][0] * inv[nt]);
          o.y = f2bf(acc[mt][nt][1] * inv[nt]);
          o.z = f2bf(acc[mt][nt][2] * inv[nt]);
          o.w = f2bf(acc[mt][nt][3] * inv[nt]);
          *(ushort4*)&qtb[(long)(n0 + nt * 16 + lr) * kD + w * 64 + mt * 16 + lq * 4] = o;
        }
    } else {  // kb[c][n] + fused kmean
      unsigned short* kbb = kb + (long)b * kD * kN;
#pragma unroll
      for (int mt = 0; mt < 4; ++mt)
#pragma unroll
        for (int rr = 0; rr < 4; ++rr) {
          const int ch = w * 64 + mt * 16 + lq * 4 + rr;
          float ks = 0.f;
#pragma unroll
          for (int nt = 0; nt < 4; ++nt) {
            const unsigned short sv = f2bf(acc[mt][nt][rr] * inv[nt]);
            kbb[(long)ch * kN + n0 + nt * 16 + lr] = sv;
            ks += bf2f(sv);
          }
          ks += __shfl_xor(ks, 1);
          ks += __shfl_xor(ks, 2);
          ks += __shfl_xor(ks, 4);
          ks += __shfl_xor(ks, 8);
          if (lr == 0) atomicAdd(&km[b * kD + ch], ks * (1.f / kN));
        }
    }
  } else {  // v: bias only -> vb[c][n]
    unsigned short* vbb = vb + (long)b * kD * kN;
#pragma unroll
    for (int mt = 0; mt < 4; ++mt)
#pragma unroll
      for (int rr = 0; rr < 4; ++rr) {
        const int ch = w * 64 + mt * 16 + lq * 4 + rr;
        const float bv = sBias[ch];
#pragma unroll
        for (int nt = 0; nt < 4; ++nt)
          vbb[(long)ch * kN + n0 + nt * 16 + lr] = f2bf(acc[mt][nt][rr] + bv);
      }
  }
}

// ---------------------------------------------------------------------------
// Tpart[s][b][i][j] = sum_{n in slice s} vb[i][n] * kb[j][n]  (MFMA, 8-way K)
// Round-0 structure + k-slice XOR swizzle.
// ---------------------------------------------------------------------------
__global__ __launch_bounds__(256) void vkt4_mfma(
    const unsigned short* __restrict__ vb, const unsigned short* __restrict__ kb,
    float* __restrict__ Tpart) {
  __shared__ unsigned short sA[128 * 32] __attribute__((aligned(16)));
  __shared__ unsigned short sB[128 * 32] __attribute__((aligned(16)));
  const int tid = threadIdx.x;
  const int i0 = blockIdx.x * 128, j0 = blockIdx.y * 128;
  const int b = blockIdx.z >> 3, s = blockIdx.z & 7;
  const unsigned short* vbb = vb + (long)b * kD * kN;
  const unsigned short* kbb = kb + (long)b * kD * kN;
  const int lane = tid & 63, w = tid >> 6;
  const int wm = (w & 1) * 64, wn = (w >> 1) * 64;
  const int lr = lane & 15, lq = lane >> 4;
  const int sxk = (lq ^ ((lr >> 1) & 3)) * 8;
  const int c0 = tid, c1 = 256 + tid;
  const int am0 = c0 >> 2, ak0 = SWZ_SRC(c0) * 8;
  const int am1 = c1 >> 2, ak1 = SWZ_SRC(c1) * 8;

  f32x4 acc[4][4];
#pragma unroll
  for (int i = 0; i < 4; ++i)
#pragma unroll
    for (int j = 0; j < 4; ++j) acc[i][j] = (f32x4){0.f, 0.f, 0.f, 0.f};

  for (int n0 = s * 512; n0 < s * 512 + 512; n0 += 32) {
    gl_lds16(vbb + (long)(i0 + am0) * kN + n0 + ak0, &sA[c0 * 8]);
    gl_lds16(vbb + (long)(i0 + am1) * kN + n0 + ak1, &sA[c1 * 8]);
    gl_lds16(kbb + (long)(j0 + am0) * kN + n0 + ak0, &sB[c0 * 8]);
    gl_lds16(kbb + (long)(j0 + am1) * kN + n0 + ak1, &sB[c1 * 8]);
    __syncthreads();
    bf16x8 af[4], bf[4];
#pragma unroll
    for (int mt = 0; mt < 4; ++mt)
      af[mt] = *(const bf16x8*)&sA[(wm + mt * 16 + lr) * 32 + sxk];
#pragma unroll
    for (int nt = 0; nt < 4; ++nt)
      bf[nt] = *(const bf16x8*)&sB[(wn + nt * 16 + lr) * 32 + sxk];
#pragma unroll
    for (int mt = 0; mt < 4; ++mt)
#pragma unroll
      for (int nt = 0; nt < 4; ++nt)
        acc[mt][nt] = __builtin_amdgcn_mfma_f32_16x16x32_bf16(
            af[mt], bf[nt], acc[mt][nt], 0, 0, 0);
    __syncthreads();
  }
  float* Tp = Tpart + ((long)s * kB + b) * kD * kD;
#pragma unroll
  for (int mt = 0; mt < 4; ++mt)
#pragma unroll
    for (int nt = 0; nt < 4; ++nt) {
      const int j = j0 + wn + nt * 16 + lr;
#pragma unroll
      for (int r = 0; r < 4; ++r) {
        const int i = i0 + wm + mt * 16 + lq * 4 + r;
        Tp[(long)i * kD + j] = acc[mt][nt][r];
      }
    }
}

// ---------------------------------------------------------------------------
// Tt[b][i][j] bf16 = (1/N) * sum_s Tpart[s][b][i][j]
// ---------------------------------------------------------------------------
__global__ __launch_bounds__(256) void tconvert(
    const float* __restrict__ Tpart, unsigned short* __restrict__ Tt) {
  const long idx = (long)blockIdx.x * 256 + threadIdx.x;
  float s = 0.f;
#pragma unroll
  for (int p = 0; p < 8; ++p) s += Tpart[(long)p * 1048576 + idx];
  Tt[idx] = f2bf(s * (1.f / 4096.f));
}

// ---------------------------------------------------------------------------
// Depthwise 5x5 conv: vb bf16 -> dwp bf16 (incl. bias).
// ---------------------------------------------------------------------------
__global__ __launch_bounds__(256) void dwconv3(
    const unsigned short* __restrict__ vb, const float* __restrict__ dwc_w,
    const float* __restrict__ dwc_b, unsigned short* __restrict__ dwp) {
  __shared__ float tile[68][80];
  __shared__ float wt[32];
  const int c = blockIdx.x, b = blockIdx.y;
  const int tid = threadIdx.x;
  if (tid < 25) wt[tid] = dwc_w[c * 25 + tid];
  {  // zero the whole tile (simple halo init): 68*80/4 = 1360 float4
    const float4 z4 = {0.f, 0.f, 0.f, 0.f};
    float* tf = &tile[0][0];
#pragma unroll
    for (int r = 0; r < 6; ++r) {
      const int i = tid + r * 256;
      if (i < 1360) *(float4*)(tf + i * 4) = z4;
    }
  }
  __syncthreads();
  const unsigned short* vp = vb + ((long)b * kD + c) * kN;
#pragma unroll
  for (int r = 0; r < 2; ++r) {  // 512 uint4 chunks (8 bf16 each)
    const int ch = tid + r * 256;
    const int row = ch >> 3, sub = ch & 7;
    const uint4 u = *(const uint4*)(vp + row * 64 + sub * 8);
    const unsigned short* p = (const unsigned short*)&u;
    float4 f0, f1;
    f0.x = bf2f(p[0]); f0.y = bf2f(p[1]); f0.z = bf2f(p[2]); f0.w = bf2f(p[3]);
    f1.x = bf2f(p[4]); f1.y = bf2f(p[5]); f1.z = bf2f(p[6]); f1.w = bf2f(p[7]);
    *(float4*)&tile[row + 2][4 + sub * 8] = f0;
    *(float4*)&tile[row + 2][8 + sub * 8] = f1;
  }
  __syncthreads();
  float w_[25];
#pragma unroll
  for (int i = 0; i < 25; ++i) w_[i] = wt[i];
  const float bias = dwc_b[c];
  const int pr = tid >> 4, pc = tid & 15;
  const int oy0 = pr * 4, ox0 = pc * 4;
  float win[8][12];
#pragma unroll
  for (int r = 0; r < 8; ++r) {
    *(float4*)&win[r][0] = *(const float4*)&tile[oy0 + r][ox0 + 0];
    *(float4*)&win[r][4] = *(const float4*)&tile[oy0 + r][ox0 + 4];
    *(float4*)&win[r][8] = *(const float4*)&tile[oy0 + r][ox0 + 8];
  }
  unsigned short* yp = dwp + ((long)b * kD + c) * kN;
#pragma unroll
  for (int dy = 0; dy < 4; ++dy) {
    ushort4 o;
    unsigned short* op = (unsigned short*)&o;
#pragma unroll
    for (int dx = 0; dx < 4; ++dx) {
      float s = bias;
#pragma unroll
      for (int ky = 0; ky < 5; ++ky)
#pragma unroll
        for (int kx = 0; kx < 5; ++kx)
          s += win[dy + ky][dx + kx + 2] * w_[ky * 5 + kx];
      op[dx] = f2bf(s);
    }
    *(ushort4*)&yp[(oy0 + dy) * 64 + ox0] = o;
  }
}

// ---------------------------------------------------------------------------
// attn: D[pix][ch] = sum_j qt[n][j] Tt[ch][j]; fused z (kmean.q), /z,
// RMSNorm over ch, *norm_w, + dw  -> yt[n][ch] bf16.
// Round-0 structure + k-slice XOR swizzle.
// ---------------------------------------------------------------------------
__global__ __launch_bounds__(256) void attn4_mfma(
    const unsigned short* __restrict__ qt, const unsigned short* __restrict__ Tt,
    const float* __restrict__ kmean, const float* __restrict__ norm_w,
    const unsigned short* __restrict__ dwp, unsigned short* __restrict__ yt) {
  __shared__ unsigned char smem[36864] __attribute__((aligned(16)));
  __shared__ float sKm[256];
  __shared__ float sNw[256];
  __shared__ float zbuf[64];
  __shared__ float rbuf[4][64];
  unsigned short* sQ = (unsigned short*)smem;            // 64 x 32
  unsigned short* sT = (unsigned short*)(smem + 4096);   // 256 x 32
  unsigned short* sDw = (unsigned short*)smem;           // 256 x 72 (reuse)
  const int tid = threadIdx.x;
  const int n0 = blockIdx.x * 64, b = blockIdx.y;
  const unsigned short* qtb = qt + (long)b * kN * kD;
  const unsigned short* Ttb = Tt + (long)b * kD * kD;
  sKm[tid] = kmean[b * kD + tid];
  sNw[tid] = norm_w[tid];
  const int lane = tid & 63, w = tid >> 6;
  const int lr = lane & 15, lq = lane >> 4;
  const int sxk = (lq ^ ((lr >> 1) & 3)) * 8;

  f32x4 acc[4][4];
#pragma unroll
  for (int i = 0; i < 4; ++i)
#pragma unroll
    for (int j = 0; j < 4; ++j) acc[i][j] = (f32x4){0.f, 0.f, 0.f, 0.f};
  float zp[4] = {0.f, 0.f, 0.f, 0.f};

  for (int k0 = 0; k0 < 256; k0 += 32) {
    {
      const int c = tid;
      gl_lds16(qtb + (long)(n0 + (c >> 2)) * kD + k0 + SWZ_SRC(c) * 8,
               &sQ[c * 8]);
    }
#pragma unroll
    for (int r = 0; r < 4; ++r) {
      const int c = tid + r * 256;
      gl_lds16(Ttb + (long)(c >> 2) * kD + k0 + SWZ_SRC(c) * 8, &sT[c * 8]);
    }
    __syncthreads();
    bf16x8 af[4], bf[4];
#pragma unroll
    for (int mt = 0; mt < 4; ++mt)
      af[mt] = *(const bf16x8*)&sQ[(mt * 16 + lr) * 32 + sxk];
#pragma unroll
    for (int nt = 0; nt < 4; ++nt)
      bf[nt] = *(const bf16x8*)&sT[(w * 64 + nt * 16 + lr) * 32 + sxk];
#pragma unroll
    for (int mt = 0; mt < 4; ++mt)
#pragma unroll
      for (int j = 0; j < 8; ++j)
        zp[mt] += bf2f((unsigned short)af[mt][j]) * sKm[k0 + lq * 8 + j];
#pragma unroll
    for (int mt = 0; mt < 4; ++mt)
#pragma unroll
      for (int nt = 0; nt < 4; ++nt)
        acc[mt][nt] = __builtin_amdgcn_mfma_f32_16x16x32_bf16(
            af[mt], bf[nt], acc[mt][nt], 0, 0, 0);
    __syncthreads();
  }

  const unsigned short* dwpb = dwp + (long)b * kD * kN;
#pragma unroll
  for (int it = 0; it < 8; ++it) {
    const int c = tid + it * 256;
    const int row = c >> 3, sub = c & 7;
    uint4 t4 = *(const uint4*)(dwpb + (long)row * kN + n0 + sub * 8);
    *(uint4*)&sDw[row * 72 + sub * 8] = t4;
  }
#pragma unroll
  for (int mt = 0; mt < 4; ++mt) {
    zp[mt] += __shfl_xor(zp[mt], 16);
    zp[mt] += __shfl_xor(zp[mt], 32);
  }
  if (w == 0 && lq == 0)
#pragma unroll
    for (int mt = 0; mt < 4; ++mt) zbuf[mt * 16 + lr] = zp[mt];
  __syncthreads();

  float ss[4][4];
#pragma unroll
  for (int mt = 0; mt < 4; ++mt)
#pragma unroll
    for (int r = 0; r < 4; ++r) {
      const float invz = 1.f / (zbuf[mt * 16 + lq * 4 + r] + FLA_EPS);
      float s = 0.f;
#pragma unroll
      for (int nt = 0; nt < 4; ++nt) {
        acc[mt][nt][r] *= invz;
        s += acc[mt][nt][r] * acc[mt][nt][r];
      }
      ss[mt][r] = s;
    }
#pragma unroll
  for (int mt = 0; mt < 4; ++mt)
#pragma unroll
    for (int r = 0; r < 4; ++r) {
      ss[mt][r] += __shfl_xor(ss[mt][r], 1);
      ss[mt][r] += __shfl_xor(ss[mt][r], 2);
      ss[mt][r] += __shfl_xor(ss[mt][r], 4);
      ss[mt][r] += __shfl_xor(ss[mt][r], 8);
    }
  if (lr == 0)
#pragma unroll
    for (int mt = 0; mt < 4; ++mt)
#pragma unroll
      for (int r = 0; r < 4; ++r) rbuf[w][mt * 16 + lq * 4 + r] = ss[mt][r];
  __syncthreads();

  unsigned short* ytb = yt + (long)b * kN * kD;
  float nw[4];
#pragma unroll
  for (int nt = 0; nt < 4; ++nt) nw[nt] = sNw[w * 64 + nt * 16 + lr];
#pragma unroll
  for (int mt = 0; mt < 4; ++mt)
#pragma unroll
    for (int r = 0; r < 4; ++r) {
      const int p = mt * 16 + lq * 4 + r;
      const float S = rbuf[0][p] + rbuf[1][p] + rbuf[2][p] + rbuf[3][p];
      const float scl = rsqrtf(S * (1.f / 256.f) + FLA_EPS);
#pragma unroll
      for (int nt = 0; nt < 4; ++nt) {
        const int ch = w * 64 + nt * 16 + lr;
        const float dw = bf2f(sDw[ch * 72 + p]);
        const float o = acc[mt][nt][r] * scl * nw[nt] + dw;
        ytb[(long)(n0 + p) * kD + ch] = f2bf(o);
      }
    }
}

// ---------------------------------------------------------------------------
// proj: out[b][c][n] = proj_w @ yt^T + proj_b  (MFMA, fp32 out)
// Round-0 structure + k-slice XOR swizzle.
// ---------------------------------------------------------------------------
__global__ __launch_bounds__(256) void proj4_mfma(
    const unsigned short* __restrict__ Wb, const unsigned short* __restrict__ yt,
    const float* __restrict__ bias, float* __restrict__ out) {
  __shared__ unsigned short sA[128 * 32] __attribute__((aligned(16)));
  __shared__ unsigned short sB[128 * 32] __attribute__((aligned(16)));
  const int tid = threadIdx.x;
  const int n0 = blockIdx.x * 128, m0 = blockIdx.y * 128, b = blockIdx.z;
  const unsigned short* ytb = yt + (long)b * kN * kD;
  const int lane = tid & 63, w = tid >> 6;
  const int wm = (w & 1) * 64, wn = (w >> 1) * 64;
  const int lr = lane & 15, lq = lane >> 4;
  const int sxk = (lq ^ ((lr >> 1) & 3)) * 8;
  const int c0 = tid, c1 = 256 + tid;
  const int am0 = c0 >> 2, ak0 = SWZ_SRC(c0) * 8;
  const int am1 = c1 >> 2, ak1 = SWZ_SRC(c1) * 8;

  f32x4 acc[4][4];
#pragma unroll
  for (int i = 0; i < 4; ++i)
#pragma unroll
    for (int j = 0; j < 4; ++j) acc[i][j] = (f32x4){0.f, 0.f, 0.f, 0.f};

  for (int k0 = 0; k0 < 256; k0 += 32) {
    gl_lds16(Wb + (long)(m0 + am0) * kD + k0 + ak0, &sA[c0 * 8]);
    gl_lds16(Wb + (long)(m0 + am1) * kD + k0 + ak1, &sA[c1 * 8]);
    gl_lds16(ytb + (long)(n0 + am0) * kD + k0 + ak0, &sB[c0 * 8]);
    gl_lds16(ytb + (long)(n0 + am1) * kD + k0 + ak1, &sB[c1 * 8]);
    __syncthreads();
    bf16x8 af[4], bf[4];
#pragma unroll
    for (int mt = 0; mt < 4; ++mt)
      af[mt] = *(const bf16x8*)&sA[(wm + mt * 16 + lr) * 32 + sxk];
#pragma unroll
    for (int nt = 0; nt < 4; ++nt)
      bf[nt] = *(const bf16x8*)&sB[(wn + nt * 16 + lr) * 32 + sxk];
#pragma unroll
    for (int mt = 0; mt < 4; ++mt)
#pragma unroll
      for (int nt = 0; nt < 4; ++nt)
        acc[mt][nt] = __builtin_amdgcn_mfma_f32_16x16x32_bf16(
            af[mt], bf[nt], acc[mt][nt], 0, 0, 0);
    __syncthreads();
  }
  float* ob = out + (long)b * kD * kN;
#pragma unroll
  for (int mt = 0; mt < 4; ++mt)
#pragma unroll
    for (int nt = 0; nt < 4; ++nt) {
      const int n = n0 + wn + nt * 16 + lr;
#pragma unroll
      for (int r = 0; r < 4; ++r) {
        const int m = m0 + wm + mt * 16 + lq * 4 + r;
        ob[(long)m * kN + n] = acc[mt][nt][r] + bias[m];
      }
    }
}

// ---------------------------------------------------------------------------
extern "C" void kernel_launch(void* const* d_in, const int* in_sizes, int n_in,
                              void* d_out, int out_size, void* d_ws,
                              size_t ws_size, hipStream_t stream) {
  const float* x      = (const float*)d_in[0];
  const float* qkv_w  = (const float*)d_in[1];
  const float* qkv_b  = (const float*)d_in[2];
  const float* dwc_w  = (const float*)d_in[3];
  const float* dwc_b  = (const float*)d_in[4];
  const float* norm_w = (const float*)d_in[5];
  const float* proj_w = (const float*)d_in[6];
  const float* proj_b = (const float*)d_in[7];
  float* out = (float*)d_out;
  char* ws = (char*)d_ws;

  constexpr long SZ = 33554432;  // 16*4096*256 * 2B
  unsigned short* qt  = (unsigned short*)(ws);
  unsigned short* kb  = (unsigned short*)(ws + SZ);
  unsigned short* vb  = (unsigned short*)(ws + 2 * SZ);
  unsigned short* dwp = (unsigned short*)(ws + 3 * SZ);
  unsigned short* yt  = (unsigned short*)(ws + 4 * SZ);
  unsigned short* xt  = (unsigned short*)(ws + 5 * SZ);
  float* Tpart        = (float*)(ws + 5 * SZ);        // aliases xt (dead)
  unsigned short* Tt  = (unsigned short*)(ws + 6 * SZ);
  unsigned short* wqb = (unsigned short*)(ws + 6 * SZ + 2097152);
  unsigned short* wpb = (unsigned short*)(ws + 6 * SZ + 2097152 + 393216);
  float* km           = (float*)(ws + 6 * SZ + 2097152 + 393216 + 131072);

  convert_w<<<768, 256, 0, stream>>>(qkv_w, wqb, kO3 * kD);
  convert_w<<<256, 256, 0, stream>>>(proj_w, wpb, kD * kD);
  transpose_x2<<<dim3(64, 4, 16), 256, 0, stream>>>(x, xt);
  hipMemsetAsync(km, 0, kB * kD * sizeof(float), stream);  // fused kmean accum
  qkv6_mfma<<<dim3(64, 3, 16), 256, 0, stream>>>(wqb, xt, qkv_b, qt, kb, vb, km);
  vkt4_mfma<<<dim3(2, 2, 128), 256, 0, stream>>>(vb, kb, Tpart);
  tconvert<<<4096, 256, 0, stream>>>(Tpart, Tt);
  dwconv3<<<dim3(256, 16), 256, 0, stream>>>(vb, dwc_w, dwc_b, dwp);
  attn4_mfma<<<dim3(64, 16), 256, 0, stream>>>(qt, Tt, km, norm_w, dwp, yt);
  proj4_mfma<<<dim3(32, 2, 16), 256, 0, stream>>>(wpb, yt, proj_b, out);
}

// Round 4
// 294.540 us; speedup vs baseline: 1.3423x; 1.0264x over previous
//
#include <hip/hip_runtime.h>
#include <math.h>
#include <stdint.h>

#define FLA_EPS 1e-5f

constexpr int kB  = 16;
constexpr int kD  = 256;   // d == C == 256
constexpr int kN  = 4096;  // H*W
constexpr int kO3 = 768;   // 3*d

typedef __attribute__((ext_vector_type(8))) short bf16x8;
typedef __attribute__((ext_vector_type(4))) float f32x4;

__device__ __forceinline__ unsigned short f2bf(float f) {
  union { float f; uint32_t u; } v; v.f = f;
  uint32_t r = v.u + 0x7FFFu + ((v.u >> 16) & 1u);  // RNE
  return (unsigned short)(r >> 16);
}
__device__ __forceinline__ float bf2f(unsigned short h) {
  union { uint32_t u; float f; } v; v.u = ((uint32_t)h) << 16; return v.f;
}
__device__ __forceinline__ void gl_lds16(const void* g, void* l) {
  __builtin_amdgcn_global_load_lds(
      (const __attribute__((address_space(1))) uint32_t*)g,
      (__attribute__((address_space(3))) uint32_t*)l, 16, 0, 0);
}

// ---------------------------------------------------------------------------
// fp32 -> bf16 weight convert
// ---------------------------------------------------------------------------
__global__ __launch_bounds__(256) void convert_w(
    const float* __restrict__ w, unsigned short* __restrict__ wb, int n) {
  const int i = blockIdx.x * 256 + threadIdx.x;
  if (i < n) wb[i] = f2bf(w[i]);
}

// ---------------------------------------------------------------------------
// x [B][C][N] fp32 -> xt [B][N][C] bf16. 64x64 tiles, float4 loads,
// ushort4 packed stores.
// ---------------------------------------------------------------------------
__global__ __launch_bounds__(256) void transpose_x2(
    const float* __restrict__ x, unsigned short* __restrict__ xt) {
  __shared__ float t[64][65];
  const int tid = threadIdx.x;
  const int n0 = blockIdx.x * 64, c0 = blockIdx.y * 64, b = blockIdx.z;
  const float* xb = x + ((long)b * kD + c0) * kN + n0;
#pragma unroll
  for (int r = 0; r < 4; ++r) {
    const int idx = tid + r * 256;  // 1024 float4 total
    const int c = idx >> 4, n4 = (idx & 15) * 4;
    const float4 v = *(const float4*)(xb + (long)c * kN + n4);
    t[c][n4] = v.x; t[c][n4 + 1] = v.y; t[c][n4 + 2] = v.z; t[c][n4 + 3] = v.w;
  }
  __syncthreads();
  unsigned short* xtb = xt + ((long)b * kN + n0) * kD + c0;
#pragma unroll
  for (int r = 0; r < 4; ++r) {
    const int idx = tid + r * 256;
    const int n = idx >> 4, cg = (idx & 15) * 4;
    ushort4 o;
    o.x = f2bf(t[cg + 0][n]); o.y = f2bf(t[cg + 1][n]);
    o.z = f2bf(t[cg + 2][n]); o.w = f2bf(t[cg + 3][n]);
    *(ushort4*)&xtb[(long)n * kD + cg] = o;
  }
}

// ---------------------------------------------------------------------------
// Fused qkv GEMM + feature map. Round-0 staging pattern (verified fastest).
// type 0 (q): feature-map, write qt[n][c] bf16 (transposed)
// type 1 (k): feature-map, write kb[c][n] bf16, fused kmean atomicAdd
// type 2 (v): bias only,  write vb[c][n] bf16
// ---------------------------------------------------------------------------
__global__ __launch_bounds__(256) void qkv7_mfma(
    const unsigned short* __restrict__ Wb, const unsigned short* __restrict__ xt,
    const float* __restrict__ bias, unsigned short* __restrict__ qt,
    unsigned short* __restrict__ kb, unsigned short* __restrict__ vb,
    float* __restrict__ km) {
  __shared__ unsigned short sA[256 * 32] __attribute__((aligned(16)));
  __shared__ unsigned short sB[64 * 32] __attribute__((aligned(16)));
  __shared__ float sBias[256];
  __shared__ float colbuf[4][64];
  const int tid = threadIdx.x;
  const int n0 = blockIdx.x * 64, type = blockIdx.y, b = blockIdx.z;
  const int m0 = type * 256;
  const unsigned short* xtb = xt + (long)b * kN * kD;
  const int lane = tid & 63, w = tid >> 6;
  const int lr = lane & 15, lq = lane >> 4;
  sBias[tid] = bias[m0 + tid];

  f32x4 acc[4][4];
#pragma unroll
  for (int i = 0; i < 4; ++i)
#pragma unroll
    for (int j = 0; j < 4; ++j) acc[i][j] = (f32x4){0.f, 0.f, 0.f, 0.f};

  for (int k0 = 0; k0 < 256; k0 += 32) {
#pragma unroll
    for (int r = 0; r < 4; ++r) {  // A: 256 rows x 32k = 1024 chunks
      const int c = tid + r * 256;
      gl_lds16(Wb + (long)(m0 + (c >> 2)) * 256 + k0 + (c & 3) * 8, &sA[c * 8]);
    }
    {  // B: 64 rows x 32k = 256 chunks
      const int c = tid;
      gl_lds16(xtb + (long)(n0 + (c >> 2)) * kD + k0 + (c & 3) * 8, &sB[c * 8]);
    }
    __syncthreads();
    bf16x8 af[4], bfr[4];
#pragma unroll
    for (int mt = 0; mt < 4; ++mt)
      af[mt] = *(const bf16x8*)&sA[(w * 64 + mt * 16 + lr) * 32 + lq * 8];
#pragma unroll
    for (int nt = 0; nt < 4; ++nt)
      bfr[nt] = *(const bf16x8*)&sB[(nt * 16 + lr) * 32 + lq * 8];
#pragma unroll
    for (int mt = 0; mt < 4; ++mt)
#pragma unroll
      for (int nt = 0; nt < 4; ++nt)
        acc[mt][nt] = __builtin_amdgcn_mfma_f32_16x16x32_bf16(
            af[mt], bfr[nt], acc[mt][nt], 0, 0, 0);
    __syncthreads();
  }

  if (type < 2) {
    float part[4] = {0.f, 0.f, 0.f, 0.f};
#pragma unroll
    for (int mt = 0; mt < 4; ++mt) {
#pragma unroll
      for (int rr = 0; rr < 4; ++rr) {
        const float bv = sBias[w * 64 + mt * 16 + lq * 4 + rr];
#pragma unroll
        for (int nt = 0; nt < 4; ++nt) {
          const float r_ = fmaxf(acc[mt][nt][rr] + bv, 0.f) + FLA_EPS;
          const float t = r_ * r_;
          acc[mt][nt][rr] = t;
          part[nt] += t * t;
        }
      }
    }
#pragma unroll
    for (int nt = 0; nt < 4; ++nt) {
      part[nt] += __shfl_xor(part[nt], 16);
      part[nt] += __shfl_xor(part[nt], 32);
    }
    if (lq == 0)
#pragma unroll
      for (int nt = 0; nt < 4; ++nt) colbuf[w][nt * 16 + lr] = part[nt];
    __syncthreads();
    float inv[4];
#pragma unroll
    for (int nt = 0; nt < 4; ++nt) {
      const int col = nt * 16 + lr;
      const float S = colbuf[0][col] + colbuf[1][col] + colbuf[2][col] + colbuf[3][col];
      inv[nt] = 1.f / fmaxf(sqrtf(S), 1e-12f);
    }
    if (type == 0) {  // qt[n][c]
      unsigned short* qtb = qt + (long)b * kN * kD;
#pragma unroll
      for (int mt = 0; mt < 4; ++mt)
#pragma unroll
        for (int nt = 0; nt < 4; ++nt) {
          ushort4 o;
          o.x = f2bf(acc[mt][nt][0] * inv[nt]);
          o.y = f2bf(acc[mt][nt][1] * inv[nt]);
          o.z = f2bf(acc[mt][nt][2] * inv[nt]);
          o.w = f2bf(acc[mt][nt][3] * inv[nt]);
          *(ushort4*)&qtb[(long)(n0 + nt * 16 + lr) * kD + w * 64 + mt * 16 + lq * 4] = o;
        }
    } else {  // kb[c][n] + fused kmean
      unsigned short* kbb = kb + (long)b * kD * kN;
#pragma unroll
      for (int mt = 0; mt < 4; ++mt)
#pragma unroll
        for (int rr = 0; rr < 4; ++rr) {
          const int ch = w * 64 + mt * 16 + lq * 4 + rr;
          float ks = 0.f;
#pragma unroll
          for (int nt = 0; nt < 4; ++nt) {
            const unsigned short sv = f2bf(acc[mt][nt][rr] * inv[nt]);
            kbb[(long)ch * kN + n0 + nt * 16 + lr] = sv;
            ks += bf2f(sv);
          }
          ks += __shfl_xor(ks, 1);
          ks += __shfl_xor(ks, 2);
          ks += __shfl_xor(ks, 4);
          ks += __shfl_xor(ks, 8);
          if (lr == 0) atomicAdd(&km[b * kD + ch], ks * (1.f / kN));
        }
    }
  } else {  // v: bias only -> vb[c][n]
    unsigned short* vbb = vb + (long)b * kD * kN;
#pragma unroll
    for (int mt = 0; mt < 4; ++mt)
#pragma unroll
      for (int rr = 0; rr < 4; ++rr) {
        const int ch = w * 64 + mt * 16 + lq * 4 + rr;
        const float bv = sBias[ch];
#pragma unroll
        for (int nt = 0; nt < 4; ++nt)
          vbb[(long)ch * kN + n0 + nt * 16 + lr] = f2bf(acc[mt][nt][rr] + bv);
      }
  }
}

// ---------------------------------------------------------------------------
// Tpart[s][b][i][j] = sum_{n in slice s} vb[i][n] * kb[j][n]  (round-0)
// ---------------------------------------------------------------------------
__global__ __launch_bounds__(256) void vkt2_mfma(
    const unsigned short* __restrict__ vb, const unsigned short* __restrict__ kb,
    float* __restrict__ Tpart) {
  __shared__ unsigned short sA[128 * 32] __attribute__((aligned(16)));
  __shared__ unsigned short sB[128 * 32] __attribute__((aligned(16)));
  const int tid = threadIdx.x;
  const int i0 = blockIdx.x * 128, j0 = blockIdx.y * 128;
  const int b = blockIdx.z >> 3, s = blockIdx.z & 7;
  const unsigned short* vbb = vb + (long)b * kD * kN;
  const unsigned short* kbb = kb + (long)b * kD * kN;
  const int lane = tid & 63, w = tid >> 6;
  const int wm = (w & 1) * 64, wn = (w >> 1) * 64;
  const int lr = lane & 15, lq = lane >> 4;
  const int c0 = tid, c1 = 256 + tid;
  const int am0 = c0 >> 2, ak0 = (c0 & 3) * 8;
  const int am1 = c1 >> 2, ak1 = (c1 & 3) * 8;

  f32x4 acc[4][4];
#pragma unroll
  for (int i = 0; i < 4; ++i)
#pragma unroll
    for (int j = 0; j < 4; ++j) acc[i][j] = (f32x4){0.f, 0.f, 0.f, 0.f};

  for (int n0 = s * 512; n0 < s * 512 + 512; n0 += 32) {
    gl_lds16(vbb + (long)(i0 + am0) * kN + n0 + ak0, &sA[c0 * 8]);
    gl_lds16(vbb + (long)(i0 + am1) * kN + n0 + ak1, &sA[c1 * 8]);
    gl_lds16(kbb + (long)(j0 + am0) * kN + n0 + ak0, &sB[c0 * 8]);
    gl_lds16(kbb + (long)(j0 + am1) * kN + n0 + ak1, &sB[c1 * 8]);
    __syncthreads();
    bf16x8 af[4], bf[4];
#pragma unroll
    for (int mt = 0; mt < 4; ++mt)
      af[mt] = *(const bf16x8*)&sA[(wm + mt * 16 + lr) * 32 + lq * 8];
#pragma unroll
    for (int nt = 0; nt < 4; ++nt)
      bf[nt] = *(const bf16x8*)&sB[(wn + nt * 16 + lr) * 32 + lq * 8];
#pragma unroll
    for (int mt = 0; mt < 4; ++mt)
#pragma unroll
      for (int nt = 0; nt < 4; ++nt)
        acc[mt][nt] = __builtin_amdgcn_mfma_f32_16x16x32_bf16(
            af[mt], bf[nt], acc[mt][nt], 0, 0, 0);
    __syncthreads();
  }
  float* Tp = Tpart + ((long)s * kB + b) * kD * kD;
#pragma unroll
  for (int mt = 0; mt < 4; ++mt)
#pragma unroll
    for (int nt = 0; nt < 4; ++nt) {
      const int j = j0 + wn + nt * 16 + lr;
#pragma unroll
      for (int r = 0; r < 4; ++r) {
        const int i = i0 + wm + mt * 16 + lq * 4 + r;
        Tp[(long)i * kD + j] = acc[mt][nt][r];
      }
    }
}

// ---------------------------------------------------------------------------
// Tt[b][i][j] bf16 = (1/N) * sum_s Tpart[s][b][i][j]
// ---------------------------------------------------------------------------
__global__ __launch_bounds__(256) void tconvert(
    const float* __restrict__ Tpart, unsigned short* __restrict__ Tt) {
  const long idx = (long)blockIdx.x * 256 + threadIdx.x;
  float s = 0.f;
#pragma unroll
  for (int p = 0; p < 8; ++p) s += Tpart[(long)p * 1048576 + idx];
  Tt[idx] = f2bf(s * (1.f / 4096.f));
}

// ---------------------------------------------------------------------------
// Depthwise 5x5 conv: vb bf16 -> dwp bf16 (incl. bias).
// ---------------------------------------------------------------------------
__global__ __launch_bounds__(256) void dwconv3(
    const unsigned short* __restrict__ vb, const float* __restrict__ dwc_w,
    const float* __restrict__ dwc_b, unsigned short* __restrict__ dwp) {
  __shared__ float tile[68][80];
  __shared__ float wt[32];
  const int c = blockIdx.x, b = blockIdx.y;
  const int tid = threadIdx.x;
  if (tid < 25) wt[tid] = dwc_w[c * 25 + tid];
  {  // zero the whole tile (simple halo init): 68*80/4 = 1360 float4
    const float4 z4 = {0.f, 0.f, 0.f, 0.f};
    float* tf = &tile[0][0];
#pragma unroll
    for (int r = 0; r < 6; ++r) {
      const int i = tid + r * 256;
      if (i < 1360) *(float4*)(tf + i * 4) = z4;
    }
  }
  __syncthreads();
  const unsigned short* vp = vb + ((long)b * kD + c) * kN;
#pragma unroll
  for (int r = 0; r < 2; ++r) {  // 512 uint4 chunks (8 bf16 each)
    const int ch = tid + r * 256;
    const int row = ch >> 3, sub = ch & 7;
    const uint4 u = *(const uint4*)(vp + row * 64 + sub * 8);
    const unsigned short* p = (const unsigned short*)&u;
    float4 f0, f1;
    f0.x = bf2f(p[0]); f0.y = bf2f(p[1]); f0.z = bf2f(p[2]); f0.w = bf2f(p[3]);
    f1.x = bf2f(p[4]); f1.y = bf2f(p[5]); f1.z = bf2f(p[6]); f1.w = bf2f(p[7]);
    *(float4*)&tile[row + 2][4 + sub * 8] = f0;
    *(float4*)&tile[row + 2][8 + sub * 8] = f1;
  }
  __syncthreads();
  float w_[25];
#pragma unroll
  for (int i = 0; i < 25; ++i) w_[i] = wt[i];
  const float bias = dwc_b[c];
  const int pr = tid >> 4, pc = tid & 15;
  const int oy0 = pr * 4, ox0 = pc * 4;
  float win[8][12];
#pragma unroll
  for (int r = 0; r < 8; ++r) {
    *(float4*)&win[r][0] = *(const float4*)&tile[oy0 + r][ox0 + 0];
    *(float4*)&win[r][4] = *(const float4*)&tile[oy0 + r][ox0 + 4];
    *(float4*)&win[r][8] = *(const float4*)&tile[oy0 + r][ox0 + 8];
  }
  unsigned short* yp = dwp + ((long)b * kD + c) * kN;
#pragma unroll
  for (int dy = 0; dy < 4; ++dy) {
    ushort4 o;
    unsigned short* op = (unsigned short*)&o;
#pragma unroll
    for (int dx = 0; dx < 4; ++dx) {
      float s = bias;
#pragma unroll
      for (int ky = 0; ky < 5; ++ky)
#pragma unroll
        for (int kx = 0; kx < 5; ++kx)
          s += win[dy + ky][dx + kx + 2] * w_[ky * 5 + kx];
      op[dx] = f2bf(s);
    }
    *(ushort4*)&yp[(oy0 + dy) * 64 + ox0] = o;
  }
}

// ---------------------------------------------------------------------------
// Fused attn + proj. Per block: 64 pixels, all 256 channels.
// Phase 1 (attn): D[pix][ch] = sum_j qt[n][j] Tt[ch][j]; fused z, /z,
//                 RMSNorm, *norm_w, + dw  -> y tile in LDS (bf16, [64][264]).
// Phase 2 (proj): out[c][n] = sum_ch P[c][ch] y[n][ch] + proj_b, fp32 stores.
// Removes the yt global round-trip (96 MB HBM) and the proj kernel.
// ---------------------------------------------------------------------------
__global__ __launch_bounds__(256) void attnproj_mfma(
    const unsigned short* __restrict__ qt, const unsigned short* __restrict__ Tt,
    const float* __restrict__ kmean, const float* __restrict__ norm_w,
    const unsigned short* __restrict__ dwp, const unsigned short* __restrict__ Pw,
    const float* __restrict__ proj_b, float* __restrict__ out) {
  __shared__ unsigned char smem[36864] __attribute__((aligned(16)));
  __shared__ unsigned short sY[64 * 264] __attribute__((aligned(16)));
  __shared__ float sKm[256];
  __shared__ float sNw[256];
  __shared__ float zbuf[64];
  __shared__ float rbuf[4][64];
  unsigned short* sQ = (unsigned short*)smem;            // 64 x 32
  unsigned short* sT = (unsigned short*)(smem + 4096);   // 256 x 32
  unsigned short* sDw = (unsigned short*)smem;           // 256 x 72 (reuse)
  unsigned short* sP = (unsigned short*)smem;            // 256 x 32 (reuse)
  const int tid = threadIdx.x;
  const int n0 = blockIdx.x * 64, b = blockIdx.y;
  const unsigned short* qtb = qt + (long)b * kN * kD;
  const unsigned short* Ttb = Tt + (long)b * kD * kD;
  sKm[tid] = kmean[b * kD + tid];
  sNw[tid] = norm_w[tid];
  const int lane = tid & 63, w = tid >> 6;
  const int lr = lane & 15, lq = lane >> 4;

  f32x4 acc[4][4];
#pragma unroll
  for (int i = 0; i < 4; ++i)
#pragma unroll
    for (int j = 0; j < 4; ++j) acc[i][j] = (f32x4){0.f, 0.f, 0.f, 0.f};
  float zp[4] = {0.f, 0.f, 0.f, 0.f};

  for (int k0 = 0; k0 < 256; k0 += 32) {
    {
      const int c = tid;
      gl_lds16(qtb + (long)(n0 + (c >> 2)) * kD + k0 + (c & 3) * 8, &sQ[c * 8]);
    }
#pragma unroll
    for (int r = 0; r < 4; ++r) {
      const int c = tid + r * 256;
      gl_lds16(Ttb + (long)(c >> 2) * kD + k0 + (c & 3) * 8, &sT[c * 8]);
    }
    __syncthreads();
    bf16x8 af[4], bf[4];
#pragma unroll
    for (int mt = 0; mt < 4; ++mt)
      af[mt] = *(const bf16x8*)&sQ[(mt * 16 + lr) * 32 + lq * 8];
#pragma unroll
    for (int nt = 0; nt < 4; ++nt)
      bf[nt] = *(const bf16x8*)&sT[(w * 64 + nt * 16 + lr) * 32 + lq * 8];
#pragma unroll
    for (int mt = 0; mt < 4; ++mt)
#pragma unroll
      for (int j = 0; j < 8; ++j)
        zp[mt] += bf2f((unsigned short)af[mt][j]) * sKm[k0 + lq * 8 + j];
#pragma unroll
    for (int mt = 0; mt < 4; ++mt)
#pragma unroll
      for (int nt = 0; nt < 4; ++nt)
        acc[mt][nt] = __builtin_amdgcn_mfma_f32_16x16x32_bf16(
            af[mt], bf[nt], acc[mt][nt], 0, 0, 0);
    __syncthreads();
  }

  const unsigned short* dwpb = dwp + (long)b * kD * kN;
#pragma unroll
  for (int it = 0; it < 8; ++it) {
    const int c = tid + it * 256;
    const int row = c >> 3, sub = c & 7;
    uint4 t4 = *(const uint4*)(dwpb + (long)row * kN + n0 + sub * 8);
    *(uint4*)&sDw[row * 72 + sub * 8] = t4;
  }
#pragma unroll
  for (int mt = 0; mt < 4; ++mt) {
    zp[mt] += __shfl_xor(zp[mt], 16);
    zp[mt] += __shfl_xor(zp[mt], 32);
  }
  if (w == 0 && lq == 0)
#pragma unroll
    for (int mt = 0; mt < 4; ++mt) zbuf[mt * 16 + lr] = zp[mt];
  __syncthreads();

  float ss[4][4];
#pragma unroll
  for (int mt = 0; mt < 4; ++mt)
#pragma unroll
    for (int r = 0; r < 4; ++r) {
      const float invz = 1.f / (zbuf[mt * 16 + lq * 4 + r] + FLA_EPS);
      float s = 0.f;
#pragma unroll
      for (int nt = 0; nt < 4; ++nt) {
        acc[mt][nt][r] *= invz;
        s += acc[mt][nt][r] * acc[mt][nt][r];
      }
      ss[mt][r] = s;
    }
#pragma unroll
  for (int mt = 0; mt < 4; ++mt)
#pragma unroll
    for (int r = 0; r < 4; ++r) {
      ss[mt][r] += __shfl_xor(ss[mt][r], 1);
      ss[mt][r] += __shfl_xor(ss[mt][r], 2);
      ss[mt][r] += __shfl_xor(ss[mt][r], 4);
      ss[mt][r] += __shfl_xor(ss[mt][r], 8);
    }
  if (lr == 0)
#pragma unroll
    for (int mt = 0; mt < 4; ++mt)
#pragma unroll
      for (int r = 0; r < 4; ++r) rbuf[w][mt * 16 + lq * 4 + r] = ss[mt][r];
  __syncthreads();

  // epilogue: y = attn*scl*nw + dw  -> sY[p][ch], bf16, row stride 264
  float nw[4];
#pragma unroll
  for (int nt = 0; nt < 4; ++nt) nw[nt] = sNw[w * 64 + nt * 16 + lr];
#pragma unroll
  for (int mt = 0; mt < 4; ++mt)
#pragma unroll
    for (int r = 0; r < 4; ++r) {
      const int p = mt * 16 + lq * 4 + r;
      const float S = rbuf[0][p] + rbuf[1][p] + rbuf[2][p] + rbuf[3][p];
      const float scl = rsqrtf(S * (1.f / 256.f) + FLA_EPS);
#pragma unroll
      for (int nt = 0; nt < 4; ++nt) {
        const int ch = w * 64 + nt * 16 + lr;
        const float dw = bf2f(sDw[ch * 72 + p]);
        sY[p * 264 + ch] = f2bf(acc[mt][nt][r] * scl * nw[nt] + dw);
      }
    }
  __syncthreads();  // sY visible to all; sDw dead -> sP may reuse smem

  // ---- proj phase: out[c][n] = sum_ch P[c][ch] y[n][ch] ----
  f32x4 acc2[4][4];
#pragma unroll
  for (int i = 0; i < 4; ++i)
#pragma unroll
    for (int j = 0; j < 4; ++j) acc2[i][j] = (f32x4){0.f, 0.f, 0.f, 0.f};
  int bo[4];
#pragma unroll
  for (int nt = 0; nt < 4; ++nt) bo[nt] = (nt * 16 + lr) * 264 + lq * 8;

  for (int kk = 0; kk < 8; ++kk) {
#pragma unroll
    for (int r = 0; r < 4; ++r) {  // P tile: 256 rows x 32k = 1024 chunks
      const int c = tid + r * 256;
      gl_lds16(Pw + (long)(c >> 2) * 256 + kk * 32 + (c & 3) * 8, &sP[c * 8]);
    }
    __syncthreads();
    bf16x8 af[4], bf[4];
#pragma unroll
    for (int mt = 0; mt < 4; ++mt)
      af[mt] = *(const bf16x8*)&sP[(w * 64 + mt * 16 + lr) * 32 + lq * 8];
#pragma unroll
    for (int nt = 0; nt < 4; ++nt)
      bf[nt] = *(const bf16x8*)&sY[bo[nt] + kk * 32];
#pragma unroll
    for (int mt = 0; mt < 4; ++mt)
#pragma unroll
      for (int nt = 0; nt < 4; ++nt)
        acc2[mt][nt] = __builtin_amdgcn_mfma_f32_16x16x32_bf16(
            af[mt], bf[nt], acc2[mt][nt], 0, 0, 0);
    __syncthreads();
  }

  float* ob = out + (long)b * kD * kN;
#pragma unroll
  for (int mt = 0; mt < 4; ++mt)
#pragma unroll
    for (int r = 0; r < 4; ++r) {
      const int m = w * 64 + mt * 16 + lq * 4 + r;
      const float pb = proj_b[m];
#pragma unroll
      for (int nt = 0; nt < 4; ++nt)
        ob[(long)m * kN + n0 + nt * 16 + lr] = acc2[mt][nt][r] + pb;
    }
}

// ---------------------------------------------------------------------------
extern "C" void kernel_launch(void* const* d_in, const int* in_sizes, int n_in,
                              void* d_out, int out_size, void* d_ws,
                              size_t ws_size, hipStream_t stream) {
  const float* x      = (const float*)d_in[0];
  const float* qkv_w  = (const float*)d_in[1];
  const float* qkv_b  = (const float*)d_in[2];
  const float* dwc_w  = (const float*)d_in[3];
  const float* dwc_b  = (const float*)d_in[4];
  const float* norm_w = (const float*)d_in[5];
  const float* proj_w = (const float*)d_in[6];
  const float* proj_b = (const float*)d_in[7];
  float* out = (float*)d_out;
  char* ws = (char*)d_ws;

  constexpr long SZ = 33554432;  // 16*4096*256 * 2B
  unsigned short* qt  = (unsigned short*)(ws);
  unsigned short* kb  = (unsigned short*)(ws + SZ);
  unsigned short* vb  = (unsigned short*)(ws + 2 * SZ);
  unsigned short* dwp = (unsigned short*)(ws + 3 * SZ);
  unsigned short* xt  = (unsigned short*)(ws + 5 * SZ);
  float* Tpart        = (float*)(ws + 5 * SZ);        // aliases xt (dead)
  unsigned short* Tt  = (unsigned short*)(ws + 6 * SZ);
  unsigned short* wqb = (unsigned short*)(ws + 6 * SZ + 2097152);
  unsigned short* wpb = (unsigned short*)(ws + 6 * SZ + 2097152 + 393216);
  float* km           = (float*)(ws + 6 * SZ + 2097152 + 393216 + 131072);

  convert_w<<<768, 256, 0, stream>>>(qkv_w, wqb, kO3 * kD);
  convert_w<<<256, 256, 0, stream>>>(proj_w, wpb, kD * kD);
  transpose_x2<<<dim3(64, 4, 16), 256, 0, stream>>>(x, xt);
  hipMemsetAsync(km, 0, kB * kD * sizeof(float), stream);  // fused kmean accum
  qkv7_mfma<<<dim3(64, 3, 16), 256, 0, stream>>>(wqb, xt, qkv_b, qt, kb, vb, km);
  vkt2_mfma<<<dim3(2, 2, 128), 256, 0, stream>>>(vb, kb, Tpart);
  tconvert<<<4096, 256, 0, stream>>>(Tpart, Tt);
  dwconv3<<<dim3(256, 16), 256, 0, stream>>>(vb, dwc_w, dwc_b, dwp);
  attnproj_mfma<<<dim3(64, 16), 256, 0, stream>>>(qt, Tt, km, norm_w, dwp,
                                                  wpb, proj_b, out);
}

// Round 5
// 285.881 us; speedup vs baseline: 1.3830x; 1.0303x over previous
//
#include <hip/hip_runtime.h>
#include <math.h>
#include <stdint.h>

#define FLA_EPS 1e-5f

constexpr int kB  = 16;
constexpr int kD  = 256;   // d == C == 256
constexpr int kN  = 4096;  // H*W
constexpr int kO3 = 768;   // 3*d

typedef __attribute__((ext_vector_type(8))) short bf16x8;
typedef __attribute__((ext_vector_type(4))) float f32x4;

__device__ __forceinline__ unsigned short f2bf(float f) {
  union { float f; uint32_t u; } v; v.f = f;
  uint32_t r = v.u + 0x7FFFu + ((v.u >> 16) & 1u);  // RNE
  return (unsigned short)(r >> 16);
}
__device__ __forceinline__ float bf2f(unsigned short h) {
  union { uint32_t u; float f; } v; v.u = ((uint32_t)h) << 16; return v.f;
}
__device__ __forceinline__ void gl_lds16(const void* g, void* l) {
  __builtin_amdgcn_global_load_lds(
      (const __attribute__((address_space(1))) uint32_t*)g,
      (__attribute__((address_space(3))) uint32_t*)l, 16, 0, 0);
}

// ---------------------------------------------------------------------------
// fp32 -> bf16 weight convert
// ---------------------------------------------------------------------------
__global__ __launch_bounds__(256) void convert_w(
    const float* __restrict__ w, unsigned short* __restrict__ wb, int n) {
  const int i = blockIdx.x * 256 + threadIdx.x;
  if (i < n) wb[i] = f2bf(w[i]);
}

// ---------------------------------------------------------------------------
// x [B][C][N] fp32 -> xt [B][N][C] bf16. 64x64 tiles, float4 loads,
// ushort4 packed stores.
// ---------------------------------------------------------------------------
__global__ __launch_bounds__(256) void transpose_x2(
    const float* __restrict__ x, unsigned short* __restrict__ xt) {
  __shared__ float t[64][65];
  const int tid = threadIdx.x;
  const int n0 = blockIdx.x * 64, c0 = blockIdx.y * 64, b = blockIdx.z;
  const float* xb = x + ((long)b * kD + c0) * kN + n0;
#pragma unroll
  for (int r = 0; r < 4; ++r) {
    const int idx = tid + r * 256;  // 1024 float4 total
    const int c = idx >> 4, n4 = (idx & 15) * 4;
    const float4 v = *(const float4*)(xb + (long)c * kN + n4);
    t[c][n4] = v.x; t[c][n4 + 1] = v.y; t[c][n4 + 2] = v.z; t[c][n4 + 3] = v.w;
  }
  __syncthreads();
  unsigned short* xtb = xt + ((long)b * kN + n0) * kD + c0;
#pragma unroll
  for (int r = 0; r < 4; ++r) {
    const int idx = tid + r * 256;
    const int n = idx >> 4, cg = (idx & 15) * 4;
    ushort4 o;
    o.x = f2bf(t[cg + 0][n]); o.y = f2bf(t[cg + 1][n]);
    o.z = f2bf(t[cg + 2][n]); o.w = f2bf(t[cg + 3][n]);
    *(ushort4*)&xtb[(long)n * kD + cg] = o;
  }
}

// ---------------------------------------------------------------------------
// Fused qkv GEMM + feature map. Round-0 source mapping (verified fastest),
// double-buffered LDS, ONE barrier per K-step (prefetch overlaps MFMA).
// No kmean fusion (isolated as a 10us regression; kmean2 kernel instead).
// type 0 (q): feature-map, write qt[n][c] bf16 (transposed)
// type 1 (k): feature-map, write kb[c][n] bf16
// type 2 (v): bias only,  write vb[c][n] bf16
// ---------------------------------------------------------------------------
__global__ __launch_bounds__(256) void qkv8_mfma(
    const unsigned short* __restrict__ Wb, const unsigned short* __restrict__ xt,
    const float* __restrict__ bias, unsigned short* __restrict__ qt,
    unsigned short* __restrict__ kb, unsigned short* __restrict__ vb) {
  __shared__ unsigned short sA[2][256 * 32] __attribute__((aligned(16)));
  __shared__ unsigned short sB[2][64 * 32] __attribute__((aligned(16)));
  __shared__ float sBias[256];
  __shared__ float colbuf[4][64];
  const int tid = threadIdx.x;
  const int n0 = blockIdx.x * 64, type = blockIdx.y, b = blockIdx.z;
  const int m0 = type * 256;
  const unsigned short* xtb = xt + (long)b * kN * kD;
  const int lane = tid & 63, w = tid >> 6;
  const int lr = lane & 15, lq = lane >> 4;
  sBias[tid] = bias[m0 + tid];

  f32x4 acc[4][4];
#pragma unroll
  for (int i = 0; i < 4; ++i)
#pragma unroll
    for (int j = 0; j < 4; ++j) acc[i][j] = (f32x4){0.f, 0.f, 0.f, 0.f};

  // prologue: stage K-step 0 into buf 0 (round-0 mapping)
#pragma unroll
  for (int r = 0; r < 4; ++r) {
    const int c = tid + r * 256;
    gl_lds16(Wb + (long)(m0 + (c >> 2)) * 256 + (c & 3) * 8, &sA[0][c * 8]);
  }
  {
    const int c = tid;
    gl_lds16(xtb + (long)(n0 + (c >> 2)) * kD + (c & 3) * 8, &sB[0][c * 8]);
  }
  __syncthreads();

  for (int kk = 0; kk < 8; ++kk) {
    const int cur = kk & 1;
    if (kk < 7) {
      const int k0 = (kk + 1) * 32;
#pragma unroll
      for (int r = 0; r < 4; ++r) {
        const int c = tid + r * 256;
        gl_lds16(Wb + (long)(m0 + (c >> 2)) * 256 + k0 + (c & 3) * 8,
                 &sA[cur ^ 1][c * 8]);
      }
      {
        const int c = tid;
        gl_lds16(xtb + (long)(n0 + (c >> 2)) * kD + k0 + (c & 3) * 8,
                 &sB[cur ^ 1][c * 8]);
      }
    }
    bf16x8 af[4], bfr[4];
#pragma unroll
    for (int mt = 0; mt < 4; ++mt)
      af[mt] = *(const bf16x8*)&sA[cur][(w * 64 + mt * 16 + lr) * 32 + lq * 8];
#pragma unroll
    for (int nt = 0; nt < 4; ++nt)
      bfr[nt] = *(const bf16x8*)&sB[cur][(nt * 16 + lr) * 32 + lq * 8];
#pragma unroll
    for (int mt = 0; mt < 4; ++mt)
#pragma unroll
      for (int nt = 0; nt < 4; ++nt)
        acc[mt][nt] = __builtin_amdgcn_mfma_f32_16x16x32_bf16(
            af[mt], bfr[nt], acc[mt][nt], 0, 0, 0);
    __syncthreads();
  }

  if (type < 2) {
    float part[4] = {0.f, 0.f, 0.f, 0.f};
#pragma unroll
    for (int mt = 0; mt < 4; ++mt) {
#pragma unroll
      for (int rr = 0; rr < 4; ++rr) {
        const float bv = sBias[w * 64 + mt * 16 + lq * 4 + rr];
#pragma unroll
        for (int nt = 0; nt < 4; ++nt) {
          const float r_ = fmaxf(acc[mt][nt][rr] + bv, 0.f) + FLA_EPS;
          const float t = r_ * r_;
          acc[mt][nt][rr] = t;
          part[nt] += t * t;
        }
      }
    }
#pragma unroll
    for (int nt = 0; nt < 4; ++nt) {
      part[nt] += __shfl_xor(part[nt], 16);
      part[nt] += __shfl_xor(part[nt], 32);
    }
    if (lq == 0)
#pragma unroll
      for (int nt = 0; nt < 4; ++nt) colbuf[w][nt * 16 + lr] = part[nt];
    __syncthreads();
    float inv[4];
#pragma unroll
    for (int nt = 0; nt < 4; ++nt) {
      const int col = nt * 16 + lr;
      const float S = colbuf[0][col] + colbuf[1][col] + colbuf[2][col] + colbuf[3][col];
      inv[nt] = 1.f / fmaxf(sqrtf(S), 1e-12f);
    }
    if (type == 0) {  // qt[n][c]
      unsigned short* qtb = qt + (long)b * kN * kD;
#pragma unroll
      for (int mt = 0; mt < 4; ++mt)
#pragma unroll
        for (int nt = 0; nt < 4; ++nt) {
          ushort4 o;
          o.x = f2bf(acc[mt][nt][0] * inv[nt]);
          o.y = f2bf(acc[mt][nt][1] * inv[nt]);
          o.z = f2bf(acc[mt][nt][2] * inv[nt]);
          o.w = f2bf(acc[mt][nt][3] * inv[nt]);
          *(ushort4*)&qtb[(long)(n0 + nt * 16 + lr) * kD + w * 64 + mt * 16 + lq * 4] = o;
        }
    } else {  // kb[c][n]
      unsigned short* kbb = kb + (long)b * kD * kN;
#pragma unroll
      for (int mt = 0; mt < 4; ++mt)
#pragma unroll
        for (int rr = 0; rr < 4; ++rr) {
          const int ch = w * 64 + mt * 16 + lq * 4 + rr;
#pragma unroll
          for (int nt = 0; nt < 4; ++nt)
            kbb[(long)ch * kN + n0 + nt * 16 + lr] = f2bf(acc[mt][nt][rr] * inv[nt]);
        }
    }
  } else {  // v: bias only -> vb[c][n]
    unsigned short* vbb = vb + (long)b * kD * kN;
#pragma unroll
    for (int mt = 0; mt < 4; ++mt)
#pragma unroll
      for (int rr = 0; rr < 4; ++rr) {
        const int ch = w * 64 + mt * 16 + lq * 4 + rr;
        const float bv = sBias[ch];
#pragma unroll
        for (int nt = 0; nt < 4; ++nt)
          vbb[(long)ch * kN + n0 + nt * 16 + lr] = f2bf(acc[mt][nt][rr] + bv);
      }
  }
}

// ---------------------------------------------------------------------------
// kmean[b][c] = mean_n kb[b][c][n]  (round-0 version, restored)
// ---------------------------------------------------------------------------
__global__ __launch_bounds__(256) void kmean2(
    const unsigned short* __restrict__ kb, float* __restrict__ km) {
  const int c = blockIdx.x, b = blockIdx.y;
  const unsigned short* row = kb + ((long)b * kD + c) * kN;
  const int base = threadIdx.x * 16;
  float s = 0.f;
#pragma unroll
  for (int h = 0; h < 2; ++h) {
    uint4 u = *(const uint4*)(row + base + h * 8);
    const unsigned short* p = (const unsigned short*)&u;
#pragma unroll
    for (int i = 0; i < 8; ++i) s += bf2f(p[i]);
  }
#pragma unroll
  for (int m = 1; m < 64; m <<= 1) s += __shfl_xor(s, m);
  __shared__ float red[4];
  if ((threadIdx.x & 63) == 0) red[threadIdx.x >> 6] = s;
  __syncthreads();
  if (threadIdx.x == 0)
    km[b * kD + c] = (red[0] + red[1] + red[2] + red[3]) * (1.f / kN);
}

// ---------------------------------------------------------------------------
// Tpart[s][b][i][j] = sum_{n in slice s} vb[i][n] * kb[j][n]
// Round-0 mapping, double-buffered, one barrier per K-step.
// ---------------------------------------------------------------------------
__global__ __launch_bounds__(256) void vkt5_mfma(
    const unsigned short* __restrict__ vb, const unsigned short* __restrict__ kb,
    float* __restrict__ Tpart) {
  __shared__ unsigned short sA[2][128 * 32] __attribute__((aligned(16)));
  __shared__ unsigned short sB[2][128 * 32] __attribute__((aligned(16)));
  const int tid = threadIdx.x;
  const int i0 = blockIdx.x * 128, j0 = blockIdx.y * 128;
  const int b = blockIdx.z >> 3, s = blockIdx.z & 7;
  const unsigned short* vbb = vb + (long)b * kD * kN;
  const unsigned short* kbb = kb + (long)b * kD * kN;
  const int lane = tid & 63, w = tid >> 6;
  const int wm = (w & 1) * 64, wn = (w >> 1) * 64;
  const int lr = lane & 15, lq = lane >> 4;
  const int c0 = tid, c1 = 256 + tid;
  const int am0 = c0 >> 2, ak0 = (c0 & 3) * 8;
  const int am1 = c1 >> 2, ak1 = (c1 & 3) * 8;

  f32x4 acc[4][4];
#pragma unroll
  for (int i = 0; i < 4; ++i)
#pragma unroll
    for (int j = 0; j < 4; ++j) acc[i][j] = (f32x4){0.f, 0.f, 0.f, 0.f};

  const int nbase = s * 512;
  gl_lds16(vbb + (long)(i0 + am0) * kN + nbase + ak0, &sA[0][c0 * 8]);
  gl_lds16(vbb + (long)(i0 + am1) * kN + nbase + ak1, &sA[0][c1 * 8]);
  gl_lds16(kbb + (long)(j0 + am0) * kN + nbase + ak0, &sB[0][c0 * 8]);
  gl_lds16(kbb + (long)(j0 + am1) * kN + nbase + ak1, &sB[0][c1 * 8]);
  __syncthreads();

  for (int kk = 0; kk < 16; ++kk) {
    const int cur = kk & 1;
    if (kk < 15) {
      const int n0 = nbase + (kk + 1) * 32;
      gl_lds16(vbb + (long)(i0 + am0) * kN + n0 + ak0, &sA[cur ^ 1][c0 * 8]);
      gl_lds16(vbb + (long)(i0 + am1) * kN + n0 + ak1, &sA[cur ^ 1][c1 * 8]);
      gl_lds16(kbb + (long)(j0 + am0) * kN + n0 + ak0, &sB[cur ^ 1][c0 * 8]);
      gl_lds16(kbb + (long)(j0 + am1) * kN + n0 + ak1, &sB[cur ^ 1][c1 * 8]);
    }
    bf16x8 af[4], bf[4];
#pragma unroll
    for (int mt = 0; mt < 4; ++mt)
      af[mt] = *(const bf16x8*)&sA[cur][(wm + mt * 16 + lr) * 32 + lq * 8];
#pragma unroll
    for (int nt = 0; nt < 4; ++nt)
      bf[nt] = *(const bf16x8*)&sB[cur][(wn + nt * 16 + lr) * 32 + lq * 8];
#pragma unroll
    for (int mt = 0; mt < 4; ++mt)
#pragma unroll
      for (int nt = 0; nt < 4; ++nt)
        acc[mt][nt] = __builtin_amdgcn_mfma_f32_16x16x32_bf16(
            af[mt], bf[nt], acc[mt][nt], 0, 0, 0);
    __syncthreads();
  }
  float* Tp = Tpart + ((long)s * kB + b) * kD * kD;
#pragma unroll
  for (int mt = 0; mt < 4; ++mt)
#pragma unroll
    for (int nt = 0; nt < 4; ++nt) {
      const int j = j0 + wn + nt * 16 + lr;
#pragma unroll
      for (int r = 0; r < 4; ++r) {
        const int i = i0 + wm + mt * 16 + lq * 4 + r;
        Tp[(long)i * kD + j] = acc[mt][nt][r];
      }
    }
}

// ---------------------------------------------------------------------------
// Tt[b][i][j] bf16 = (1/N) * sum_s Tpart[s][b][i][j]
// ---------------------------------------------------------------------------
__global__ __launch_bounds__(256) void tconvert(
    const float* __restrict__ Tpart, unsigned short* __restrict__ Tt) {
  const long idx = (long)blockIdx.x * 256 + threadIdx.x;
  float s = 0.f;
#pragma unroll
  for (int p = 0; p < 8; ++p) s += Tpart[(long)p * 1048576 + idx];
  Tt[idx] = f2bf(s * (1.f / 4096.f));
}

// ---------------------------------------------------------------------------
// Depthwise 5x5 conv: vb bf16 -> dwp bf16 (incl. bias).
// ---------------------------------------------------------------------------
__global__ __launch_bounds__(256) void dwconv3(
    const unsigned short* __restrict__ vb, const float* __restrict__ dwc_w,
    const float* __restrict__ dwc_b, unsigned short* __restrict__ dwp) {
  __shared__ float tile[68][80];
  __shared__ float wt[32];
  const int c = blockIdx.x, b = blockIdx.y;
  const int tid = threadIdx.x;
  if (tid < 25) wt[tid] = dwc_w[c * 25 + tid];
  {  // zero the whole tile (simple halo init): 68*80/4 = 1360 float4
    const float4 z4 = {0.f, 0.f, 0.f, 0.f};
    float* tf = &tile[0][0];
#pragma unroll
    for (int r = 0; r < 6; ++r) {
      const int i = tid + r * 256;
      if (i < 1360) *(float4*)(tf + i * 4) = z4;
    }
  }
  __syncthreads();
  const unsigned short* vp = vb + ((long)b * kD + c) * kN;
#pragma unroll
  for (int r = 0; r < 2; ++r) {  // 512 uint4 chunks (8 bf16 each)
    const int ch = tid + r * 256;
    const int row = ch >> 3, sub = ch & 7;
    const uint4 u = *(const uint4*)(vp + row * 64 + sub * 8);
    const unsigned short* p = (const unsigned short*)&u;
    float4 f0, f1;
    f0.x = bf2f(p[0]); f0.y = bf2f(p[1]); f0.z = bf2f(p[2]); f0.w = bf2f(p[3]);
    f1.x = bf2f(p[4]); f1.y = bf2f(p[5]); f1.z = bf2f(p[6]); f1.w = bf2f(p[7]);
    *(float4*)&tile[row + 2][4 + sub * 8] = f0;
    *(float4*)&tile[row + 2][8 + sub * 8] = f1;
  }
  __syncthreads();
  float w_[25];
#pragma unroll
  for (int i = 0; i < 25; ++i) w_[i] = wt[i];
  const float bias = dwc_b[c];
  const int pr = tid >> 4, pc = tid & 15;
  const int oy0 = pr * 4, ox0 = pc * 4;
  float win[8][12];
#pragma unroll
  for (int r = 0; r < 8; ++r) {
    *(float4*)&win[r][0] = *(const float4*)&tile[oy0 + r][ox0 + 0];
    *(float4*)&win[r][4] = *(const float4*)&tile[oy0 + r][ox0 + 4];
    *(float4*)&win[r][8] = *(const float4*)&tile[oy0 + r][ox0 + 8];
  }
  unsigned short* yp = dwp + ((long)b * kD + c) * kN;
#pragma unroll
  for (int dy = 0; dy < 4; ++dy) {
    ushort4 o;
    unsigned short* op = (unsigned short*)&o;
#pragma unroll
    for (int dx = 0; dx < 4; ++dx) {
      float s = bias;
#pragma unroll
      for (int ky = 0; ky < 5; ++ky)
#pragma unroll
        for (int kx = 0; kx < 5; ++kx)
          s += win[dy + ky][dx + kx + 2] * w_[ky * 5 + kx];
      op[dx] = f2bf(s);
    }
    *(ushort4*)&yp[(oy0 + dy) * 64 + ox0] = o;
  }
}

// ---------------------------------------------------------------------------
// Fused attn + proj. Per block: 64 pixels, all 256 channels.
// Phase 1 (attn, dbuf): D[pix][ch] = sum_j qt[n][j] Tt[ch][j]; fused z, /z,
//                 RMSNorm, *norm_w, + dw  -> y tile in LDS (bf16, [64][264]).
// Phase 2 (proj, dbuf): out[c][n] = sum_ch P[c][ch] y[n][ch] + proj_b.
// ---------------------------------------------------------------------------
__global__ __launch_bounds__(256) void attnproj2_mfma(
    const unsigned short* __restrict__ qt, const unsigned short* __restrict__ Tt,
    const float* __restrict__ kmean, const float* __restrict__ norm_w,
    const unsigned short* __restrict__ dwp, const unsigned short* __restrict__ Pw,
    const float* __restrict__ proj_b, float* __restrict__ out) {
  __shared__ unsigned char smem[40960] __attribute__((aligned(16)));
  __shared__ unsigned short sY[64 * 264] __attribute__((aligned(16)));
  __shared__ float sKm[256];
  __shared__ float sNw[256];
  __shared__ float zbuf[64];
  __shared__ float rbuf[4][64];
  // phase1: smem = [buf][sQ 4096 | sT 16384], stride 20480
  unsigned short* sDw = (unsigned short*)smem;  // 256 x 72 (reuse after p1)
  const int tid = threadIdx.x;
  const int n0 = blockIdx.x * 64, b = blockIdx.y;
  const unsigned short* qtb = qt + (long)b * kN * kD;
  const unsigned short* Ttb = Tt + (long)b * kD * kD;
  sKm[tid] = kmean[b * kD + tid];
  sNw[tid] = norm_w[tid];
  const int lane = tid & 63, w = tid >> 6;
  const int lr = lane & 15, lq = lane >> 4;

  f32x4 acc[4][4];
#pragma unroll
  for (int i = 0; i < 4; ++i)
#pragma unroll
    for (int j = 0; j < 4; ++j) acc[i][j] = (f32x4){0.f, 0.f, 0.f, 0.f};
  float zp[4] = {0.f, 0.f, 0.f, 0.f};

  {  // prologue: stage K-step 0 into buf 0
    unsigned short* sQ = (unsigned short*)smem;
    unsigned short* sT = (unsigned short*)(smem + 4096);
    {
      const int c = tid;
      gl_lds16(qtb + (long)(n0 + (c >> 2)) * kD + (c & 3) * 8, &sQ[c * 8]);
    }
#pragma unroll
    for (int r = 0; r < 4; ++r) {
      const int c = tid + r * 256;
      gl_lds16(Ttb + (long)(c >> 2) * kD + (c & 3) * 8, &sT[c * 8]);
    }
  }
  __syncthreads();

  for (int kk = 0; kk < 8; ++kk) {
    const int cur = kk & 1;
    unsigned short* sQ = (unsigned short*)(smem + cur * 20480);
    unsigned short* sT = (unsigned short*)(smem + cur * 20480 + 4096);
    if (kk < 7) {
      const int k0 = (kk + 1) * 32;
      unsigned short* nQ = (unsigned short*)(smem + (cur ^ 1) * 20480);
      unsigned short* nT = (unsigned short*)(smem + (cur ^ 1) * 20480 + 4096);
      {
        const int c = tid;
        gl_lds16(qtb + (long)(n0 + (c >> 2)) * kD + k0 + (c & 3) * 8, &nQ[c * 8]);
      }
#pragma unroll
      for (int r = 0; r < 4; ++r) {
        const int c = tid + r * 256;
        gl_lds16(Ttb + (long)(c >> 2) * kD + k0 + (c & 3) * 8, &nT[c * 8]);
      }
    }
    bf16x8 af[4], bf[4];
#pragma unroll
    for (int mt = 0; mt < 4; ++mt)
      af[mt] = *(const bf16x8*)&sQ[(mt * 16 + lr) * 32 + lq * 8];
#pragma unroll
    for (int nt = 0; nt < 4; ++nt)
      bf[nt] = *(const bf16x8*)&sT[(w * 64 + nt * 16 + lr) * 32 + lq * 8];
#pragma unroll
    for (int mt = 0; mt < 4; ++mt)
#pragma unroll
      for (int j = 0; j < 8; ++j)
        zp[mt] += bf2f((unsigned short)af[mt][j]) * sKm[kk * 32 + lq * 8 + j];
#pragma unroll
    for (int mt = 0; mt < 4; ++mt)
#pragma unroll
      for (int nt = 0; nt < 4; ++nt)
        acc[mt][nt] = __builtin_amdgcn_mfma_f32_16x16x32_bf16(
            af[mt], bf[nt], acc[mt][nt], 0, 0, 0);
    __syncthreads();
  }

  const unsigned short* dwpb = dwp + (long)b * kD * kN;
#pragma unroll
  for (int it = 0; it < 8; ++it) {
    const int c = tid + it * 256;
    const int row = c >> 3, sub = c & 7;
    uint4 t4 = *(const uint4*)(dwpb + (long)row * kN + n0 + sub * 8);
    *(uint4*)&sDw[row * 72 + sub * 8] = t4;
  }
#pragma unroll
  for (int mt = 0; mt < 4; ++mt) {
    zp[mt] += __shfl_xor(zp[mt], 16);
    zp[mt] += __shfl_xor(zp[mt], 32);
  }
  if (w == 0 && lq == 0)
#pragma unroll
    for (int mt = 0; mt < 4; ++mt) zbuf[mt * 16 + lr] = zp[mt];
  __syncthreads();

  float ss[4][4];
#pragma unroll
  for (int mt = 0; mt < 4; ++mt)
#pragma unroll
    for (int r = 0; r < 4; ++r) {
      const float invz = 1.f / (zbuf[mt * 16 + lq * 4 + r] + FLA_EPS);
      float s = 0.f;
#pragma unroll
      for (int nt = 0; nt < 4; ++nt) {
        acc[mt][nt][r] *= invz;
        s += acc[mt][nt][r] * acc[mt][nt][r];
      }
      ss[mt][r] = s;
    }
#pragma unroll
  for (int mt = 0; mt < 4; ++mt)
#pragma unroll
    for (int r = 0; r < 4; ++r) {
      ss[mt][r] += __shfl_xor(ss[mt][r], 1);
      ss[mt][r] += __shfl_xor(ss[mt][r], 2);
      ss[mt][r] += __shfl_xor(ss[mt][r], 4);
      ss[mt][r] += __shfl_xor(ss[mt][r], 8);
    }
  if (lr == 0)
#pragma unroll
    for (int mt = 0; mt < 4; ++mt)
#pragma unroll
      for (int r = 0; r < 4; ++r) rbuf[w][mt * 16 + lq * 4 + r] = ss[mt][r];
  __syncthreads();

  // epilogue: y = attn*scl*nw + dw  -> sY[p][ch], bf16, row stride 264
  float nw[4];
#pragma unroll
  for (int nt = 0; nt < 4; ++nt) nw[nt] = sNw[w * 64 + nt * 16 + lr];
#pragma unroll
  for (int mt = 0; mt < 4; ++mt)
#pragma unroll
    for (int r = 0; r < 4; ++r) {
      const int p = mt * 16 + lq * 4 + r;
      const float S = rbuf[0][p] + rbuf[1][p] + rbuf[2][p] + rbuf[3][p];
      const float scl = rsqrtf(S * (1.f / 256.f) + FLA_EPS);
#pragma unroll
      for (int nt = 0; nt < 4; ++nt) {
        const int ch = w * 64 + nt * 16 + lr;
        const float dw = bf2f(sDw[ch * 72 + p]);
        sY[p * 264 + ch] = f2bf(acc[mt][nt][r] * scl * nw[nt] + dw);
      }
    }
  __syncthreads();  // sDw reads + sY writes done -> smem free for sP

  // ---- proj phase (dbuf): out[c][n] = sum_ch P[c][ch] y[n][ch] ----
  // sP buffers: smem + cur*16384 (2 x 16 KB fits in 40960)
  f32x4 acc2[4][4];
#pragma unroll
  for (int i = 0; i < 4; ++i)
#pragma unroll
    for (int j = 0; j < 4; ++j) acc2[i][j] = (f32x4){0.f, 0.f, 0.f, 0.f};
  int bo[4];
#pragma unroll
  for (int nt = 0; nt < 4; ++nt) bo[nt] = (nt * 16 + lr) * 264 + lq * 8;

  {  // prologue: stage P K-step 0
    unsigned short* sP = (unsigned short*)smem;
#pragma unroll
    for (int r = 0; r < 4; ++r) {
      const int c = tid + r * 256;
      gl_lds16(Pw + (long)(c >> 2) * 256 + (c & 3) * 8, &sP[c * 8]);
    }
  }
  __syncthreads();

  for (int kk = 0; kk < 8; ++kk) {
    const int cur = kk & 1;
    unsigned short* sP = (unsigned short*)(smem + cur * 16384);
    if (kk < 7) {
      unsigned short* nP = (unsigned short*)(smem + (cur ^ 1) * 16384);
#pragma unroll
      for (int r = 0; r < 4; ++r) {
        const int c = tid + r * 256;
        gl_lds16(Pw + (long)(c >> 2) * 256 + (kk + 1) * 32 + (c & 3) * 8,
                 &nP[c * 8]);
      }
    }
    bf16x8 af[4], bf[4];
#pragma unroll
    for (int mt = 0; mt < 4; ++mt)
      af[mt] = *(const bf16x8*)&sP[(w * 64 + mt * 16 + lr) * 32 + lq * 8];
#pragma unroll
    for (int nt = 0; nt < 4; ++nt)
      bf[nt] = *(const bf16x8*)&sY[bo[nt] + kk * 32];
#pragma unroll
    for (int mt = 0; mt < 4; ++mt)
#pragma unroll
      for (int nt = 0; nt < 4; ++nt)
        acc2[mt][nt] = __builtin_amdgcn_mfma_f32_16x16x32_bf16(
            af[mt], bf[nt], acc2[mt][nt], 0, 0, 0);
    __syncthreads();
  }

  float* ob = out + (long)b * kD * kN;
#pragma unroll
  for (int mt = 0; mt < 4; ++mt)
#pragma unroll
    for (int r = 0; r < 4; ++r) {
      const int m = w * 64 + mt * 16 + lq * 4 + r;
      const float pb = proj_b[m];
#pragma unroll
      for (int nt = 0; nt < 4; ++nt)
        ob[(long)m * kN + n0 + nt * 16 + lr] = acc2[mt][nt][r] + pb;
    }
}

// ---------------------------------------------------------------------------
extern "C" void kernel_launch(void* const* d_in, const int* in_sizes, int n_in,
                              void* d_out, int out_size, void* d_ws,
                              size_t ws_size, hipStream_t stream) {
  const float* x      = (const float*)d_in[0];
  const float* qkv_w  = (const float*)d_in[1];
  const float* qkv_b  = (const float*)d_in[2];
  const float* dwc_w  = (const float*)d_in[3];
  const float* dwc_b  = (const float*)d_in[4];
  const float* norm_w = (const float*)d_in[5];
  const float* proj_w = (const float*)d_in[6];
  const float* proj_b = (const float*)d_in[7];
  float* out = (float*)d_out;
  char* ws = (char*)d_ws;

  constexpr long SZ = 33554432;  // 16*4096*256 * 2B
  unsigned short* qt  = (unsigned short*)(ws);
  unsigned short* kb  = (unsigned short*)(ws + SZ);
  unsigned short* vb  = (unsigned short*)(ws + 2 * SZ);
  unsigned short* dwp = (unsigned short*)(ws + 3 * SZ);
  unsigned short* xt  = (unsigned short*)(ws + 5 * SZ);
  float* Tpart        = (float*)(ws + 5 * SZ);        // aliases xt (dead)
  unsigned short* Tt  = (unsigned short*)(ws + 6 * SZ);
  unsigned short* wqb = (unsigned short*)(ws + 6 * SZ + 2097152);
  unsigned short* wpb = (unsigned short*)(ws + 6 * SZ + 2097152 + 393216);
  float* km           = (float*)(ws + 6 * SZ + 2097152 + 393216 + 131072);

  convert_w<<<768, 256, 0, stream>>>(qkv_w, wqb, kO3 * kD);
  convert_w<<<256, 256, 0, stream>>>(proj_w, wpb, kD * kD);
  transpose_x2<<<dim3(64, 4, 16), 256, 0, stream>>>(x, xt);
  qkv8_mfma<<<dim3(64, 3, 16), 256, 0, stream>>>(wqb, xt, qkv_b, qt, kb, vb);
  kmean2<<<dim3(256, 16), 256, 0, stream>>>(kb, km);
  vkt5_mfma<<<dim3(2, 2, 128), 256, 0, stream>>>(vb, kb, Tpart);
  tconvert<<<4096, 256, 0, stream>>>(Tpart, Tt);
  dwconv3<<<dim3(256, 16), 256, 0, stream>>>(vb, dwc_w, dwc_b, dwp);
  attnproj2_mfma<<<dim3(64, 16), 256, 0, stream>>>(qt, Tt, km, norm_w, dwp,
                                                   wpb, proj_b, out);
}